// Round 1
// baseline (4029.414 us; speedup 1.0000x reference)
//
#include <hip/hip_runtime.h>
#include <hip/hip_bf16.h>
#include <math.h>

#define B_ 4
#define S_ 100
#define T_ 2048
#define DM 128
#define NH 8
#define DH 16
#define NL 6
#define DFFN 512

#define SQRT_D 11.313708498984761f   // sqrt(128)
#define LN10K  9.210340371976184f    // ln(10000)

// ---------------------------------------------------------------- posenc
__device__ __forceinline__ float pe_val(int pos, int d) {
    int i = d >> 1;
    float dv = __expf((float)i * (-2.0f * LN10K / 128.0f));
    float ang = (float)pos * dv;
    return (d & 1) ? __cosf(ang) : __sinf(ang);
}

// ---------------------------------------------------------------- embeds
__global__ __launch_bounds__(256) void embed_src_kernel(
    const int* __restrict__ src, const float* __restrict__ emb, float* __restrict__ out)
{
    int idx = blockIdx.x * 256 + threadIdx.x;
    if (idx >= B_ * S_ * DM) return;
    int d = idx & 127;
    int row = idx >> 7;          // b*100 + s
    int b = row / S_;
    int tok = src[row];
    out[idx] = emb[tok * DM + d] * SQRT_D + pe_val(b, d);
}

__global__ __launch_bounds__(256) void embed_tgt_kernel(
    const float* __restrict__ tgt, const float* __restrict__ fw,
    const float* __restrict__ fb, float* __restrict__ out)
{
    int idx = blockIdx.x * 256 + threadIdx.x;
    if (idx >= B_ * T_ * DM) return;
    int d = idx & 127;
    int row = idx >> 7;          // b*2048 + t
    int b = row >> 11;
    out[idx] = (tgt[row] * fw[d] + fb[d]) * SQRT_D + pe_val(b, d);
}

// ---------------------------------------------------------------- GEMM (NT): C[M,N] = A[M,K] @ W[N,K]^T + bias, opt ReLU
// BM=BN=64, BK=32, 256 threads, 4x4 micro-tile. LDS stored K-major with +4 pad.
__global__ __launch_bounds__(256) void gemm_nt(
    const float* __restrict__ A, const float* __restrict__ W,
    const float* __restrict__ bias, float* __restrict__ C,
    int M, int N, int K, int relu)
{
    __shared__ float As[32][68];
    __shared__ float Ws[32][68];
    const int t = threadIdx.x;
    const int tn = t & 15, tm = t >> 4;
    const int row0 = blockIdx.x * 64, col0 = blockIdx.y * 64;

    float acc[4][4];
    #pragma unroll
    for (int i = 0; i < 4; i++)
        #pragma unroll
        for (int j = 0; j < 4; j++) acc[i][j] = 0.0f;

    for (int k0 = 0; k0 < K; k0 += 32) {
        #pragma unroll
        for (int i = 0; i < 2; i++) {
            int idx = t + i * 256;           // 0..511
            int r  = idx >> 3;               // 0..63
            int c4 = (idx & 7) << 2;         // 0,4,...,28
            int gr = row0 + r;
            float4 a = make_float4(0.f, 0.f, 0.f, 0.f);
            if (gr < M) a = *(const float4*)&A[(size_t)gr * K + k0 + c4];
            As[c4 + 0][r] = a.x; As[c4 + 1][r] = a.y;
            As[c4 + 2][r] = a.z; As[c4 + 3][r] = a.w;
            int gc = col0 + r;               // N is always a multiple of 64 here
            float4 w = *(const float4*)&W[(size_t)gc * K + k0 + c4];
            Ws[c4 + 0][r] = w.x; Ws[c4 + 1][r] = w.y;
            Ws[c4 + 2][r] = w.z; Ws[c4 + 3][r] = w.w;
        }
        __syncthreads();
        #pragma unroll
        for (int kk = 0; kk < 32; kk++) {
            float4 av = *(const float4*)&As[kk][tm * 4];
            float4 wv = *(const float4*)&Ws[kk][tn * 4];
            float a4[4] = {av.x, av.y, av.z, av.w};
            float w4[4] = {wv.x, wv.y, wv.z, wv.w};
            #pragma unroll
            for (int i = 0; i < 4; i++)
                #pragma unroll
                for (int j = 0; j < 4; j++)
                    acc[i][j] = fmaf(a4[i], w4[j], acc[i][j]);
        }
        __syncthreads();
    }

    int col = col0 + tn * 4;
    float4 bv = *(const float4*)&bias[col];
    #pragma unroll
    for (int i = 0; i < 4; i++) {
        int row = row0 + tm * 4 + i;
        if (row < M) {
            float4 cv;
            cv.x = acc[i][0] + bv.x; cv.y = acc[i][1] + bv.y;
            cv.z = acc[i][2] + bv.z; cv.w = acc[i][3] + bv.w;
            if (relu) {
                cv.x = fmaxf(cv.x, 0.f); cv.y = fmaxf(cv.y, 0.f);
                cv.z = fmaxf(cv.z, 0.f); cv.w = fmaxf(cv.w, 0.f);
            }
            *(float4*)&C[(size_t)row * N + col] = cv;
        }
    }
}

// ---------------------------------------------------------------- flash attention (f32)
// grid: (ceil(Lq/256), H, B); one thread per q-row of one head. K/V tiles of 64 in LDS.
__global__ __launch_bounds__(256) void attn_kernel(
    const float* __restrict__ Q, int qs,
    const float* __restrict__ Kp, int ks,
    const float* __restrict__ Vp, int vs,
    float* __restrict__ O, int os,
    int Lq, int Lk)
{
    __shared__ float Ks[64][16];
    __shared__ float Vs[64][16];
    const int b = blockIdx.z, h = blockIdx.y;
    const int q = blockIdx.x * 256 + threadIdx.x;
    const bool active = (q < Lq);

    const float* qp = Q + ((size_t)b * Lq + (active ? q : 0)) * qs + h * DH;
    float qv[16];
    #pragma unroll
    for (int d = 0; d < 16; d++) qv[d] = qp[d] * 0.25f;   // 1/sqrt(16)

    const float* kb = Kp + (size_t)b * Lk * ks + h * DH;
    const float* vb = Vp + (size_t)b * Lk * vs + h * DH;

    float m = -1e30f, l = 0.0f, o[16];
    #pragma unroll
    for (int d = 0; d < 16; d++) o[d] = 0.0f;

    for (int k0 = 0; k0 < Lk; k0 += 64) {
        int r = threadIdx.x >> 2, c4 = (threadIdx.x & 3) << 2;
        int gk = k0 + r;
        float4 z = make_float4(0.f, 0.f, 0.f, 0.f);
        float4 kk4 = (gk < Lk) ? *(const float4*)&kb[(size_t)gk * ks + c4] : z;
        float4 vv4 = (gk < Lk) ? *(const float4*)&vb[(size_t)gk * vs + c4] : z;
        __syncthreads();
        *(float4*)&Ks[r][c4] = kk4;
        *(float4*)&Vs[r][c4] = vv4;
        __syncthreads();

        int kn = Lk - k0;     // valid keys this tile (may exceed 64)
        float s[64];
        float tmax = -1e30f;
        #pragma unroll
        for (int j = 0; j < 64; j++) {
            float a = 0.0f;
            #pragma unroll
            for (int d = 0; d < 16; d++) a = fmaf(qv[d], Ks[j][d], a);
            s[j] = (j < kn) ? a : -1e30f;
            tmax = fmaxf(tmax, s[j]);
        }
        float mnew = fmaxf(m, tmax);
        float corr = __expf(m - mnew);
        l *= corr;
        #pragma unroll
        for (int d = 0; d < 16; d++) o[d] *= corr;
        #pragma unroll
        for (int j = 0; j < 64; j++) {
            float p = __expf(s[j] - mnew);   // padded lanes underflow to 0
            l += p;
            #pragma unroll
            for (int d = 0; d < 16; d++) o[d] = fmaf(p, Vs[j][d], o[d]);
        }
        m = mnew;
    }

    if (active) {
        float inv = 1.0f / l;
        float* op = O + ((size_t)b * Lq + q) * os + h * DH;
        #pragma unroll
        for (int d = 0; d < 16; d++) op[d] = o[d] * inv;
    }
}

// ---------------------------------------------------------------- residual + LayerNorm (in place on y)
__global__ __launch_bounds__(256) void add_ln_kernel(
    float* __restrict__ y, const float* __restrict__ res,
    const float* __restrict__ g, const float* __restrict__ bta, int M)
{
    int row = blockIdx.x * 4 + (threadIdx.x >> 6);
    int lane = threadIdx.x & 63;
    if (row >= M) return;
    float* yr = y + (size_t)row * DM;
    float x0 = yr[lane], x1 = yr[lane + 64];
    if (res) {
        const float* rr = res + (size_t)row * DM;
        x0 += rr[lane]; x1 += rr[lane + 64];
    }
    float sum = x0 + x1;
    #pragma unroll
    for (int off = 32; off > 0; off >>= 1) sum += __shfl_xor(sum, off, 64);
    float mean = sum * (1.0f / 128.0f);
    float d0 = x0 - mean, d1 = x1 - mean;
    float vs = d0 * d0 + d1 * d1;
    #pragma unroll
    for (int off = 32; off > 0; off >>= 1) vs += __shfl_xor(vs, off, 64);
    float rstd = rsqrtf(vs * (1.0f / 128.0f) + 1e-5f);
    yr[lane]      = d0 * rstd * g[lane]      + bta[lane];
    yr[lane + 64] = d1 * rstd * g[lane + 64] + bta[lane + 64];
}

// ---------------------------------------------------------------- final: out = tgt + eta * (y @ fc_w^T + fc_b)
__global__ __launch_bounds__(256) void final_kernel(
    const float* __restrict__ y, const float* __restrict__ tgt,
    const float* __restrict__ fcw, const float* __restrict__ fcb,
    float* __restrict__ out)
{
    int row = blockIdx.x * 4 + (threadIdx.x >> 6);
    int lane = threadIdx.x & 63;
    const float* yr = y + (size_t)row * DM;
    float a = yr[lane] * fcw[lane] + yr[lane + 64] * fcw[lane + 64];
    #pragma unroll
    for (int off = 32; off > 0; off >>= 1) a += __shfl_xor(a, off, 64);
    if (lane == 0) out[row] = tgt[row] + 1.0e-3f * (a + fcb[0]);
}

// ---------------------------------------------------------------- launcher
extern "C" void kernel_launch(void* const* d_in, const int* in_sizes, int n_in,
                              void* d_out, int out_size, void* d_ws, size_t ws_size,
                              hipStream_t stream)
{
    (void)in_sizes; (void)n_in; (void)out_size; (void)ws_size;
    const int*   src     = (const int*)  d_in[0];
    const float* tgt     = (const float*)d_in[1];
    const float* emb     = (const float*)d_in[2];
    const float* femb_w  = (const float*)d_in[3];
    const float* femb_b  = (const float*)d_in[4];
    const float* enc_inw = (const float*)d_in[5];
    const float* enc_inb = (const float*)d_in[6];
    const float* enc_ow  = (const float*)d_in[7];
    const float* enc_ob  = (const float*)d_in[8];
    const float* enc_l1g = (const float*)d_in[9];
    const float* enc_l1b = (const float*)d_in[10];
    const float* enc_l2g = (const float*)d_in[11];
    const float* enc_l2b = (const float*)d_in[12];
    const float* enc_f1w = (const float*)d_in[13];
    const float* enc_f1b = (const float*)d_in[14];
    const float* enc_f2w = (const float*)d_in[15];
    const float* enc_f2b = (const float*)d_in[16];
    const float* enc_ng  = (const float*)d_in[17];
    const float* enc_nb  = (const float*)d_in[18];
    const float* dec_inw = (const float*)d_in[19];
    const float* dec_inb = (const float*)d_in[20];
    const float* dec_ow  = (const float*)d_in[21];
    const float* dec_ob  = (const float*)d_in[22];
    const float* dec_cinw= (const float*)d_in[23];
    const float* dec_cinb= (const float*)d_in[24];
    const float* dec_cow = (const float*)d_in[25];
    const float* dec_cob = (const float*)d_in[26];
    const float* dec_l1g = (const float*)d_in[27];
    const float* dec_l1b = (const float*)d_in[28];
    const float* dec_l2g = (const float*)d_in[29];
    const float* dec_l2b = (const float*)d_in[30];
    const float* dec_l3g = (const float*)d_in[31];
    const float* dec_l3b = (const float*)d_in[32];
    const float* dec_f1w = (const float*)d_in[33];
    const float* dec_f1b = (const float*)d_in[34];
    const float* dec_f2w = (const float*)d_in[35];
    const float* dec_f2b = (const float*)d_in[36];
    const float* dec_ng  = (const float*)d_in[37];
    const float* dec_nb  = (const float*)d_in[38];
    const float* fc_w    = (const float*)d_in[39];
    const float* fc_b    = (const float*)d_in[40];

    float* ws    = (float*)d_ws;
    float* mem   = ws;                       // 400*128
    float* kvbuf = mem   + 400 * 128;        // 400*256
    float* ybuf  = kvbuf + 400 * 256;        // 8192*128
    float* big   = ybuf  + 8192 * 128;       // 8192*512 (qkv / ffn hidden / cross-q)
    float* aout  = big   + 8192 * 512;       // 8192*128
    float* tmp   = aout  + 8192 * 128;       // 8192*128

    // ---------------- encoder (M = 400 rows) ----------------
    embed_src_kernel<<<200, 256, 0, stream>>>(src, emb, mem);
    for (int i = 0; i < NL; i++) {
        gemm_nt<<<dim3(7, 6), 256, 0, stream>>>(mem, enc_inw + i * 49152, enc_inb + i * 384, big, 400, 384, 128, 0);
        attn_kernel<<<dim3(1, NH, B_), 256, 0, stream>>>(big, 384, big + 128, 384, big + 256, 384, aout, 128, 100, 100);
        gemm_nt<<<dim3(7, 2), 256, 0, stream>>>(aout, enc_ow + i * 16384, enc_ob + i * 128, tmp, 400, 128, 128, 0);
        add_ln_kernel<<<100, 256, 0, stream>>>(mem, tmp, enc_l1g + i * 128, enc_l1b + i * 128, 400);
        gemm_nt<<<dim3(7, 8), 256, 0, stream>>>(mem, enc_f1w + i * 65536, enc_f1b + i * 512, big, 400, 512, 128, 1);
        gemm_nt<<<dim3(7, 2), 256, 0, stream>>>(big, enc_f2w + i * 65536, enc_f2b + i * 128, tmp, 400, 128, 512, 0);
        add_ln_kernel<<<100, 256, 0, stream>>>(mem, tmp, enc_l2g + i * 128, enc_l2b + i * 128, 400);
    }
    add_ln_kernel<<<100, 256, 0, stream>>>(mem, nullptr, enc_ng, enc_nb, 400);

    // ---------------- decoder (M = 8192 rows) ----------------
    embed_tgt_kernel<<<4096, 256, 0, stream>>>(tgt, femb_w, femb_b, ybuf);
    for (int i = 0; i < NL; i++) {
        // self-attention
        gemm_nt<<<dim3(128, 6), 256, 0, stream>>>(ybuf, dec_inw + i * 49152, dec_inb + i * 384, big, 8192, 384, 128, 0);
        attn_kernel<<<dim3(8, NH, B_), 256, 0, stream>>>(big, 384, big + 128, 384, big + 256, 384, aout, 128, 2048, 2048);
        gemm_nt<<<dim3(128, 2), 256, 0, stream>>>(aout, dec_ow + i * 16384, dec_ob + i * 128, tmp, 8192, 128, 128, 0);
        add_ln_kernel<<<2048, 256, 0, stream>>>(ybuf, tmp, dec_l1g + i * 128, dec_l1b + i * 128, 8192);
        // cross-attention
        gemm_nt<<<dim3(128, 2), 256, 0, stream>>>(ybuf, dec_cinw + i * 49152, dec_cinb + i * 384, big, 8192, 128, 128, 0);
        gemm_nt<<<dim3(7, 4), 256, 0, stream>>>(mem, dec_cinw + i * 49152 + 16384, dec_cinb + i * 384 + 128, kvbuf, 400, 256, 128, 0);
        attn_kernel<<<dim3(8, NH, B_), 256, 0, stream>>>(big, 128, kvbuf, 256, kvbuf + 128, 256, aout, 128, 2048, 100);
        gemm_nt<<<dim3(128, 2), 256, 0, stream>>>(aout, dec_cow + i * 16384, dec_cob + i * 128, tmp, 8192, 128, 128, 0);
        add_ln_kernel<<<2048, 256, 0, stream>>>(ybuf, tmp, dec_l2g + i * 128, dec_l2b + i * 128, 8192);
        // FFN
        gemm_nt<<<dim3(128, 8), 256, 0, stream>>>(ybuf, dec_f1w + i * 65536, dec_f1b + i * 512, big, 8192, 512, 128, 1);
        gemm_nt<<<dim3(128, 2), 256, 0, stream>>>(big, dec_f2w + i * 65536, dec_f2b + i * 128, tmp, 8192, 128, 512, 0);
        add_ln_kernel<<<2048, 256, 0, stream>>>(ybuf, tmp, dec_l3g + i * 128, dec_l3b + i * 128, 8192);
    }
    add_ln_kernel<<<2048, 256, 0, stream>>>(ybuf, nullptr, dec_ng, dec_nb, 8192);
    final_kernel<<<2048, 256, 0, stream>>>(ybuf, tgt, fc_w, fc_b, (float*)d_out);
}

// Round 2
// 1717.162 us; speedup vs baseline: 2.3466x; 2.3466x over previous
//
#include <hip/hip_runtime.h>
#include <hip/hip_bf16.h>
#include <math.h>

#define B_ 4
#define S_ 100
#define T_ 2048
#define DM 128
#define NH 8
#define DH 16
#define NL 6
#define DFFN 512

#define SQRT_D 11.313708498984761f   // sqrt(128)
#define LN10K  9.210340371976184f    // ln(10000)

typedef _Float16 v4h __attribute__((ext_vector_type(4)));
typedef float    v4f __attribute__((ext_vector_type(4)));

// ---------------------------------------------------------------- posenc
__device__ __forceinline__ float pe_val(int pos, int d) {
    int i = d >> 1;
    float dv = __expf((float)i * (-2.0f * LN10K / 128.0f));
    float ang = (float)pos * dv;
    return (d & 1) ? __cosf(ang) : __sinf(ang);
}

// ---------------------------------------------------------------- embeds
__global__ __launch_bounds__(256) void embed_src_kernel(
    const int* __restrict__ src, const float* __restrict__ emb, float* __restrict__ out)
{
    int idx = blockIdx.x * 256 + threadIdx.x;
    if (idx >= B_ * S_ * DM) return;
    int d = idx & 127;
    int row = idx >> 7;          // b*100 + s
    int b = row / S_;
    int tok = src[row];
    out[idx] = emb[tok * DM + d] * SQRT_D + pe_val(b, d);
}

__global__ __launch_bounds__(256) void embed_tgt_kernel(
    const float* __restrict__ tgt, const float* __restrict__ fw,
    const float* __restrict__ fb, float* __restrict__ out)
{
    int idx = blockIdx.x * 256 + threadIdx.x;
    if (idx >= B_ * T_ * DM) return;
    int d = idx & 127;
    int row = idx >> 7;          // b*2048 + t
    int b = row >> 11;
    out[idx] = (tgt[row] * fw[d] + fb[d]) * SQRT_D + pe_val(b, d);
}

// ---------------------------------------------------------------- GEMM (NT): C[M,N] = A[M,K] @ W[N,K]^T + bias, opt ReLU
__global__ __launch_bounds__(256) void gemm_nt(
    const float* __restrict__ A, const float* __restrict__ W,
    const float* __restrict__ bias, float* __restrict__ C,
    int M, int N, int K, int relu)
{
    __shared__ float As[32][68];
    __shared__ float Ws[32][68];
    const int t = threadIdx.x;
    const int tn = t & 15, tm = t >> 4;
    const int row0 = blockIdx.x * 64, col0 = blockIdx.y * 64;

    float acc[4][4];
    #pragma unroll
    for (int i = 0; i < 4; i++)
        #pragma unroll
        for (int j = 0; j < 4; j++) acc[i][j] = 0.0f;

    for (int k0 = 0; k0 < K; k0 += 32) {
        #pragma unroll
        for (int i = 0; i < 2; i++) {
            int idx = t + i * 256;           // 0..511
            int r  = idx >> 3;               // 0..63
            int c4 = (idx & 7) << 2;         // 0,4,...,28
            int gr = row0 + r;
            float4 a = make_float4(0.f, 0.f, 0.f, 0.f);
            if (gr < M) a = *(const float4*)&A[(size_t)gr * K + k0 + c4];
            As[c4 + 0][r] = a.x; As[c4 + 1][r] = a.y;
            As[c4 + 2][r] = a.z; As[c4 + 3][r] = a.w;
            int gc = col0 + r;               // N is always a multiple of 64 here
            float4 w = *(const float4*)&W[(size_t)gc * K + k0 + c4];
            Ws[c4 + 0][r] = w.x; Ws[c4 + 1][r] = w.y;
            Ws[c4 + 2][r] = w.z; Ws[c4 + 3][r] = w.w;
        }
        __syncthreads();
        #pragma unroll
        for (int kk = 0; kk < 32; kk++) {
            float4 av = *(const float4*)&As[kk][tm * 4];
            float4 wv = *(const float4*)&Ws[kk][tn * 4];
            float a4[4] = {av.x, av.y, av.z, av.w};
            float w4[4] = {wv.x, wv.y, wv.z, wv.w};
            #pragma unroll
            for (int i = 0; i < 4; i++)
                #pragma unroll
                for (int j = 0; j < 4; j++)
                    acc[i][j] = fmaf(a4[i], w4[j], acc[i][j]);
        }
        __syncthreads();
    }

    int col = col0 + tn * 4;
    float4 bv = *(const float4*)&bias[col];
    #pragma unroll
    for (int i = 0; i < 4; i++) {
        int row = row0 + tm * 4 + i;
        if (row < M) {
            float4 cv;
            cv.x = acc[i][0] + bv.x; cv.y = acc[i][1] + bv.y;
            cv.z = acc[i][2] + bv.z; cv.w = acc[i][3] + bv.w;
            if (relu) {
                cv.x = fmaxf(cv.x, 0.f); cv.y = fmaxf(cv.y, 0.f);
                cv.z = fmaxf(cv.z, 0.f); cv.w = fmaxf(cv.w, 0.f);
            }
            *(float4*)&C[(size_t)row * N + col] = cv;
        }
    }
}

// ---------------------------------------------------------------- MFMA flash attention (f16 in / f32 acc)
// One wave owns 16 q-rows of one head. Swapped-operand pattern:
//   S^T frag = mfma(K_frag, Q_frag): lane holds S[key=4*grp+r][q=lane&15]
//   which IS the B-operand layout (k=4*grp+i, col=lane&15) for
//   O^T = mfma(V^T_frag, P^T_frag)  -> lane holds O[q=lane&15][d=4*grp+r].
// grid: (ceil(Lq/64), H, B), 256 threads = 4 waves.
__global__ __launch_bounds__(256) void attn_mfma(
    const float* __restrict__ Q, int qs,
    const float* __restrict__ Kp, int ks,
    const float* __restrict__ Vp, int vs,
    float* __restrict__ O, int os,
    int Lq, int Lk)
{
    const int b = blockIdx.z, h = blockIdx.y;
    const int wave = threadIdx.x >> 6;
    const int lane = threadIdx.x & 63;
    const int col16 = lane & 15;     // q-row (B/D col); also A-row (key) and V^T d-index
    const int grp   = lane >> 4;     // 0..3

    const int q0 = (blockIdx.x * 4 + wave) * 16;
    const int qrow = q0 + col16;
    const int qcl = min(qrow, Lq - 1);

    // Q frag (B operand): Q[qcl][4*grp + i] * 1/sqrt(dh)
    const float* qp = Q + ((size_t)b * Lq + qcl) * qs + h * DH + grp * 4;
    float4 qv = *(const float4*)qp;
    v4h q_frag = { (_Float16)(qv.x * 0.25f), (_Float16)(qv.y * 0.25f),
                   (_Float16)(qv.z * 0.25f), (_Float16)(qv.w * 0.25f) };

    const float* kb = Kp + (size_t)b * Lk * ks + h * DH;
    const float* vb = Vp + (size_t)b * Lk * vs + h * DH;

    float m = -1e30f, l = 0.0f;
    v4f o_acc = {0.f, 0.f, 0.f, 0.f};

    for (int kc = 0; kc < Lk; kc += 64) {
        // ---- QK^T: 4 sub-tiles of 16 keys ----
        float s[16];
        #pragma unroll
        for (int sub = 0; sub < 4; sub++) {
            int krow = kc + sub * 16 + col16;         // A-operand row = key
            int kcl2 = min(krow, Lk - 1);
            float4 kv = *(const float4*)(kb + (size_t)kcl2 * ks + grp * 4);
            v4h k_frag = { (_Float16)kv.x, (_Float16)kv.y,
                           (_Float16)kv.z, (_Float16)kv.w };
            v4f sf = __builtin_amdgcn_mfma_f32_16x16x16f16(
                         k_frag, q_frag, (v4f){0.f, 0.f, 0.f, 0.f}, 0, 0, 0);
            #pragma unroll
            for (int r = 0; r < 4; r++) {
                int key = kc + sub * 16 + grp * 4 + r;
                s[sub * 4 + r] = (key < Lk) ? sf[r] : -1e30f;
            }
        }
        // ---- online softmax over this 64-key chunk ----
        float mt = -1e30f;
        #pragma unroll
        for (int r = 0; r < 16; r++) mt = fmaxf(mt, s[r]);
        mt = fmaxf(mt, __shfl_xor(mt, 16, 64));
        mt = fmaxf(mt, __shfl_xor(mt, 32, 64));
        float mnew = fmaxf(m, mt);
        float corr = __expf(m - mnew);
        float psum = 0.0f;
        _Float16 ph[16];
        #pragma unroll
        for (int r = 0; r < 16; r++) {
            float p = __expf(s[r] - mnew);    // masked keys: exp(-huge) = 0
            psum += p;
            ph[r] = (_Float16)p;
        }
        psum += __shfl_xor(psum, 16, 64);
        psum += __shfl_xor(psum, 32, 64);
        l = l * corr + psum;
        o_acc[0] *= corr; o_acc[1] *= corr;
        o_acc[2] *= corr; o_acc[3] *= corr;
        m = mnew;
        // ---- PV: O^T += V^T * P^T ----
        #pragma unroll
        for (int sub = 0; sub < 4; sub++) {
            int vrow = kc + sub * 16 + grp * 4;       // A2 k-index = key
            v4h vt_frag;
            #pragma unroll
            for (int i = 0; i < 4; i++) {
                int vr = min(vrow + i, Lk - 1);       // clamped rows hit p=0
                vt_frag[i] = (_Float16)vb[(size_t)vr * vs + col16];
            }
            v4h p_frag = { ph[sub * 4 + 0], ph[sub * 4 + 1],
                           ph[sub * 4 + 2], ph[sub * 4 + 3] };
            o_acc = __builtin_amdgcn_mfma_f32_16x16x16f16(
                        vt_frag, p_frag, o_acc, 0, 0, 0);
        }
    }

    if (qrow < Lq) {
        float inv = 1.0f / l;
        float* op = O + ((size_t)b * Lq + qrow) * os + h * DH;
        #pragma unroll
        for (int r = 0; r < 4; r++) op[grp * 4 + r] = o_acc[r] * inv;
    }
}

// ---------------------------------------------------------------- residual + LayerNorm (in place on y)
__global__ __launch_bounds__(256) void add_ln_kernel(
    float* __restrict__ y, const float* __restrict__ res,
    const float* __restrict__ g, const float* __restrict__ bta, int M)
{
    int row = blockIdx.x * 4 + (threadIdx.x >> 6);
    int lane = threadIdx.x & 63;
    if (row >= M) return;
    float* yr = y + (size_t)row * DM;
    float x0 = yr[lane], x1 = yr[lane + 64];
    if (res) {
        const float* rr = res + (size_t)row * DM;
        x0 += rr[lane]; x1 += rr[lane + 64];
    }
    float sum = x0 + x1;
    #pragma unroll
    for (int off = 32; off > 0; off >>= 1) sum += __shfl_xor(sum, off, 64);
    float mean = sum * (1.0f / 128.0f);
    float d0 = x0 - mean, d1 = x1 - mean;
    float vs = d0 * d0 + d1 * d1;
    #pragma unroll
    for (int off = 32; off > 0; off >>= 1) vs += __shfl_xor(vs, off, 64);
    float rstd = rsqrtf(vs * (1.0f / 128.0f) + 1e-5f);
    yr[lane]      = d0 * rstd * g[lane]      + bta[lane];
    yr[lane + 64] = d1 * rstd * g[lane + 64] + bta[lane + 64];
}

// ---------------------------------------------------------------- final: out = tgt + eta * (y @ fc_w^T + fc_b)
__global__ __launch_bounds__(256) void final_kernel(
    const float* __restrict__ y, const float* __restrict__ tgt,
    const float* __restrict__ fcw, const float* __restrict__ fcb,
    float* __restrict__ out)
{
    int row = blockIdx.x * 4 + (threadIdx.x >> 6);
    int lane = threadIdx.x & 63;
    const float* yr = y + (size_t)row * DM;
    float a = yr[lane] * fcw[lane] + yr[lane + 64] * fcw[lane + 64];
    #pragma unroll
    for (int off = 32; off > 0; off >>= 1) a += __shfl_xor(a, off, 64);
    if (lane == 0) out[row] = tgt[row] + 1.0e-3f * (a + fcb[0]);
}

// ---------------------------------------------------------------- launcher
extern "C" void kernel_launch(void* const* d_in, const int* in_sizes, int n_in,
                              void* d_out, int out_size, void* d_ws, size_t ws_size,
                              hipStream_t stream)
{
    (void)in_sizes; (void)n_in; (void)out_size; (void)ws_size;
    const int*   src     = (const int*)  d_in[0];
    const float* tgt     = (const float*)d_in[1];
    const float* emb     = (const float*)d_in[2];
    const float* femb_w  = (const float*)d_in[3];
    const float* femb_b  = (const float*)d_in[4];
    const float* enc_inw = (const float*)d_in[5];
    const float* enc_inb = (const float*)d_in[6];
    const float* enc_ow  = (const float*)d_in[7];
    const float* enc_ob  = (const float*)d_in[8];
    const float* enc_l1g = (const float*)d_in[9];
    const float* enc_l1b = (const float*)d_in[10];
    const float* enc_l2g = (const float*)d_in[11];
    const float* enc_l2b = (const float*)d_in[12];
    const float* enc_f1w = (const float*)d_in[13];
    const float* enc_f1b = (const float*)d_in[14];
    const float* enc_f2w = (const float*)d_in[15];
    const float* enc_f2b = (const float*)d_in[16];
    const float* enc_ng  = (const float*)d_in[17];
    const float* enc_nb  = (const float*)d_in[18];
    const float* dec_inw = (const float*)d_in[19];
    const float* dec_inb = (const float*)d_in[20];
    const float* dec_ow  = (const float*)d_in[21];
    const float* dec_ob  = (const float*)d_in[22];
    const float* dec_cinw= (const float*)d_in[23];
    const float* dec_cinb= (const float*)d_in[24];
    const float* dec_cow = (const float*)d_in[25];
    const float* dec_cob = (const float*)d_in[26];
    const float* dec_l1g = (const float*)d_in[27];
    const float* dec_l1b = (const float*)d_in[28];
    const float* dec_l2g = (const float*)d_in[29];
    const float* dec_l2b = (const float*)d_in[30];
    const float* dec_l3g = (const float*)d_in[31];
    const float* dec_l3b = (const float*)d_in[32];
    const float* dec_f1w = (const float*)d_in[33];
    const float* dec_f1b = (const float*)d_in[34];
    const float* dec_f2w = (const float*)d_in[35];
    const float* dec_f2b = (const float*)d_in[36];
    const float* dec_ng  = (const float*)d_in[37];
    const float* dec_nb  = (const float*)d_in[38];
    const float* fc_w    = (const float*)d_in[39];
    const float* fc_b    = (const float*)d_in[40];

    float* ws    = (float*)d_ws;
    float* mem   = ws;                       // 400*128
    float* kvbuf = mem   + 400 * 128;        // 400*256
    float* ybuf  = kvbuf + 400 * 256;        // 8192*128
    float* big   = ybuf  + 8192 * 128;       // 8192*512 (qkv / ffn hidden / cross-q)
    float* aout  = big   + 8192 * 512;       // 8192*128
    float* tmp   = aout  + 8192 * 128;       // 8192*128

    // ---------------- encoder (M = 400 rows) ----------------
    embed_src_kernel<<<200, 256, 0, stream>>>(src, emb, mem);
    for (int i = 0; i < NL; i++) {
        gemm_nt<<<dim3(7, 6), 256, 0, stream>>>(mem, enc_inw + i * 49152, enc_inb + i * 384, big, 400, 384, 128, 0);
        attn_mfma<<<dim3(2, NH, B_), 256, 0, stream>>>(big, 384, big + 128, 384, big + 256, 384, aout, 128, 100, 100);
        gemm_nt<<<dim3(7, 2), 256, 0, stream>>>(aout, enc_ow + i * 16384, enc_ob + i * 128, tmp, 400, 128, 128, 0);
        add_ln_kernel<<<100, 256, 0, stream>>>(mem, tmp, enc_l1g + i * 128, enc_l1b + i * 128, 400);
        gemm_nt<<<dim3(7, 8), 256, 0, stream>>>(mem, enc_f1w + i * 65536, enc_f1b + i * 512, big, 400, 512, 128, 1);
        gemm_nt<<<dim3(7, 2), 256, 0, stream>>>(big, enc_f2w + i * 65536, enc_f2b + i * 128, tmp, 400, 128, 512, 0);
        add_ln_kernel<<<100, 256, 0, stream>>>(mem, tmp, enc_l2g + i * 128, enc_l2b + i * 128, 400);
    }
    add_ln_kernel<<<100, 256, 0, stream>>>(mem, nullptr, enc_ng, enc_nb, 400);

    // ---------------- decoder (M = 8192 rows) ----------------
    embed_tgt_kernel<<<4096, 256, 0, stream>>>(tgt, femb_w, femb_b, ybuf);
    for (int i = 0; i < NL; i++) {
        // self-attention
        gemm_nt<<<dim3(128, 6), 256, 0, stream>>>(ybuf, dec_inw + i * 49152, dec_inb + i * 384, big, 8192, 384, 128, 0);
        attn_mfma<<<dim3(32, NH, B_), 256, 0, stream>>>(big, 384, big + 128, 384, big + 256, 384, aout, 128, 2048, 2048);
        gemm_nt<<<dim3(128, 2), 256, 0, stream>>>(aout, dec_ow + i * 16384, dec_ob + i * 128, tmp, 8192, 128, 128, 0);
        add_ln_kernel<<<2048, 256, 0, stream>>>(ybuf, tmp, dec_l1g + i * 128, dec_l1b + i * 128, 8192);
        // cross-attention
        gemm_nt<<<dim3(128, 2), 256, 0, stream>>>(ybuf, dec_cinw + i * 49152, dec_cinb + i * 384, big, 8192, 128, 128, 0);
        gemm_nt<<<dim3(7, 4), 256, 0, stream>>>(mem, dec_cinw + i * 49152 + 16384, dec_cinb + i * 384 + 128, kvbuf, 400, 256, 128, 0);
        attn_mfma<<<dim3(32, NH, B_), 256, 0, stream>>>(big, 128, kvbuf, 256, kvbuf + 128, 256, aout, 128, 2048, 100);
        gemm_nt<<<dim3(128, 2), 256, 0, stream>>>(aout, dec_cow + i * 16384, dec_cob + i * 128, tmp, 8192, 128, 128, 0);
        add_ln_kernel<<<2048, 256, 0, stream>>>(ybuf, tmp, dec_l2g + i * 128, dec_l2b + i * 128, 8192);
        // FFN
        gemm_nt<<<dim3(128, 8), 256, 0, stream>>>(ybuf, dec_f1w + i * 65536, dec_f1b + i * 512, big, 8192, 512, 128, 1);
        gemm_nt<<<dim3(128, 2), 256, 0, stream>>>(big, dec_f2w + i * 65536, dec_f2b + i * 128, tmp, 8192, 128, 512, 0);
        add_ln_kernel<<<2048, 256, 0, stream>>>(ybuf, tmp, dec_l3g + i * 128, dec_l3b + i * 128, 8192);
    }
    add_ln_kernel<<<2048, 256, 0, stream>>>(ybuf, nullptr, dec_ng, dec_nb, 8192);
    final_kernel<<<2048, 256, 0, stream>>>(ybuf, tgt, fc_w, fc_b, (float*)d_out);
}

// Round 3
// 1527.636 us; speedup vs baseline: 2.6377x; 1.1241x over previous
//
#include <hip/hip_runtime.h>
#include <hip/hip_bf16.h>
#include <math.h>

#define B_ 4
#define S_ 100
#define T_ 2048
#define DM 128
#define NH 8
#define DH 16
#define NL 6
#define DFFN 512

#define SQRT_D 11.313708498984761f   // sqrt(128)
#define LN10K  9.210340371976184f    // ln(10000)
#define QSCALE 0.36067376022224085f  // 0.25 * log2(e)

typedef _Float16 v4h __attribute__((ext_vector_type(4)));
typedef float    v4f __attribute__((ext_vector_type(4)));

// ---------------------------------------------------------------- posenc
__device__ __forceinline__ float pe_val(int pos, int d) {
    int i = d >> 1;
    float dv = __expf((float)i * (-2.0f * LN10K / 128.0f));
    float ang = (float)pos * dv;
    return (d & 1) ? __cosf(ang) : __sinf(ang);
}

// ---------------------------------------------------------------- weight f32->f16 conversion (once per call)
__global__ __launch_bounds__(256) void conv_w(
    const float* __restrict__ p0, const float* __restrict__ p1,
    const float* __restrict__ p2, const float* __restrict__ p3,
    const float* __restrict__ p4, const float* __restrict__ p5,
    const float* __restrict__ p6, const float* __restrict__ p7,
    const float* __restrict__ p8, const float* __restrict__ p9,
    _Float16* __restrict__ out)
{
    int seg = blockIdx.y;
    const float* s; int sz; long off;
    switch (seg) {
        case 0: s = p0; sz = 294912; off = 0;       break;
        case 1: s = p1; sz = 98304;  off = 294912;  break;
        case 2: s = p2; sz = 393216; off = 393216;  break;
        case 3: s = p3; sz = 393216; off = 786432;  break;
        case 4: s = p4; sz = 294912; off = 1179648; break;
        case 5: s = p5; sz = 98304;  off = 1474560; break;
        case 6: s = p6; sz = 294912; off = 1572864; break;
        case 7: s = p7; sz = 98304;  off = 1867776; break;
        case 8: s = p8; sz = 393216; off = 1966080; break;
        default: s = p9; sz = 393216; off = 2359296; break;
    }
    int idx = (blockIdx.x * 256 + threadIdx.x) * 4;
    if (idx >= sz) return;
    float4 v = *(const float4*)(s + idx);
    v4h h = { (_Float16)v.x, (_Float16)v.y, (_Float16)v.z, (_Float16)v.w };
    *(v4h*)(out + off + idx) = h;
}

// ---------------------------------------------------------------- embeds (write f32 + f16 shadow)
__global__ __launch_bounds__(256) void embed_src_kernel(
    const int* __restrict__ src, const float* __restrict__ emb,
    float* __restrict__ out, _Float16* __restrict__ outh)
{
    int idx = blockIdx.x * 256 + threadIdx.x;
    if (idx >= B_ * S_ * DM) return;
    int d = idx & 127;
    int row = idx >> 7;          // b*100 + s
    int b = row / S_;
    int tok = src[row];
    float v = emb[tok * DM + d] * SQRT_D + pe_val(b, d);
    out[idx] = v;
    outh[idx] = (_Float16)v;
}

__global__ __launch_bounds__(256) void embed_tgt_kernel(
    const float* __restrict__ tgt, const float* __restrict__ fw,
    const float* __restrict__ fb, float* __restrict__ out, _Float16* __restrict__ outh)
{
    int idx = blockIdx.x * 256 + threadIdx.x;
    if (idx >= B_ * T_ * DM) return;
    int d = idx & 127;
    int row = idx >> 7;          // b*2048 + t
    int b = row >> 11;
    float v = (tgt[row] * fw[d] + fb[d]) * SQRT_D + pe_val(b, d);
    out[idx] = v;
    outh[idx] = (_Float16)v;
}

// ---------------------------------------------------------------- f16 MFMA GEMM (NT): C[M,N] = A[M,K] @ W[N,K]^T + bias
// BM=128, BN=64, BK=64, 256 threads = 4 waves, each wave 64x32 via 4x2 16x16 frags.
// MODE 0: f32 C. MODE 1: f16 C + relu. MODE 2: attention pack (q scaled, k, v-transposed).
template<int MODE>
__global__ __launch_bounds__(256) void gemm_h(
    const _Float16* __restrict__ A, const _Float16* __restrict__ W,
    const float* __restrict__ bias,
    float* __restrict__ Cf, _Float16* __restrict__ Ch,
    _Float16* __restrict__ qo, _Float16* __restrict__ ko, _Float16* __restrict__ vo,
    int M, int N, int K, int L, int Lkp, int part_off, int Lshift)
{
    __shared__ _Float16 As[128][72];
    __shared__ _Float16 Ws[64][72];
    const int t = threadIdx.x;
    const int wave = t >> 6, lane = t & 63;
    const int col16 = lane & 15, grp = lane >> 4;
    const int row0 = blockIdx.x * 128, col0 = blockIdx.y * 64;
    const int wrow0 = (wave >> 1) * 64, wcol0 = (wave & 1) * 32;

    v4f acc[4][2];
    #pragma unroll
    for (int m = 0; m < 4; m++)
        #pragma unroll
        for (int n = 0; n < 2; n++) acc[m][n] = (v4f){0.f, 0.f, 0.f, 0.f};

    for (int k0 = 0; k0 < K; k0 += 64) {
        #pragma unroll
        for (int i = 0; i < 4; i++) {
            int id = i * 256 + t;            // 0..1023
            int r = id >> 3, j = id & 7;
            int gr = min(row0 + r, M - 1);
            int4 v = *(const int4*)(A + (size_t)gr * K + k0 + j * 8);
            *(int4*)&As[r][j * 8] = v;
        }
        #pragma unroll
        for (int i = 0; i < 2; i++) {
            int id = i * 256 + t;            // 0..511
            int r = id >> 3, j = id & 7;
            int4 v = *(const int4*)(W + (size_t)(col0 + r) * K + k0 + j * 8);
            *(int4*)&Ws[r][j * 8] = v;
        }
        __syncthreads();
        #pragma unroll
        for (int kk = 0; kk < 4; kk++) {
            v4h a[4], bf[2];
            #pragma unroll
            for (int m = 0; m < 4; m++)
                a[m] = *(const v4h*)&As[wrow0 + m * 16 + col16][kk * 16 + grp * 4];
            #pragma unroll
            for (int n = 0; n < 2; n++)
                bf[n] = *(const v4h*)&Ws[wcol0 + n * 16 + col16][kk * 16 + grp * 4];
            #pragma unroll
            for (int m = 0; m < 4; m++)
                #pragma unroll
                for (int n = 0; n < 2; n++)
                    acc[m][n] = __builtin_amdgcn_mfma_f32_16x16x16f16(a[m], bf[n], acc[m][n], 0, 0, 0);
        }
        __syncthreads();
    }

    // epilogue
    #pragma unroll
    for (int n = 0; n < 2; n++) {
        int gcol = col0 + wcol0 + n * 16 + col16;
        float bv = bias[gcol];
        #pragma unroll
        for (int m = 0; m < 4; m++) {
            int rbase = row0 + wrow0 + m * 16 + grp * 4;
            #pragma unroll
            for (int r = 0; r < 4; r++) {
                int grow = rbase + r;
                if (grow >= M) continue;
                float v = acc[m][n][r] + bv;
                if (MODE == 0) {
                    Cf[(size_t)grow * N + gcol] = v;
                } else if (MODE == 1) {
                    Ch[(size_t)grow * N + gcol] = (_Float16)fmaxf(v, 0.f);
                } else {
                    int pc = gcol + part_off;
                    int part = pc >> 7;
                    int h = (pc >> 4) & 7;
                    int d = pc & 15;
                    int b = Lshift ? (grow >> Lshift) : (grow / L);
                    int pos = grow - b * L;
                    int bh = b * NH + h;
                    if (part == 0)
                        qo[((size_t)bh * L + pos) * 16 + d] = (_Float16)(v * QSCALE);
                    else if (part == 1)
                        ko[((size_t)bh * L + pos) * 16 + d] = (_Float16)v;
                    else
                        vo[((size_t)bh * 16 + d) * Lkp + pos] = (_Float16)v;
                }
            }
        }
    }
}

// ---------------------------------------------------------------- MFMA flash attention on packed f16 (exp2 domain)
// qh: [B,H,Lq,16] (pre-scaled by 1/sqrt(dh)*log2e), kh: [B,H,Lk,16], vth: [B,H,16,Lkp]
// out: f16 [B*Lq, 128]. grid (ceil(Lq/64), H, B), 256 thr = 4 waves, wave owns 16 q-rows.
__global__ __launch_bounds__(256) void attn_p(
    const _Float16* __restrict__ qh, const _Float16* __restrict__ kh,
    const _Float16* __restrict__ vth, _Float16* __restrict__ outh,
    int Lq, int Lk, int Lkp)
{
    const int b = blockIdx.z, h = blockIdx.y;
    const int wave = threadIdx.x >> 6, lane = threadIdx.x & 63;
    const int col16 = lane & 15, grp = lane >> 4;
    const int bh = b * NH + h;
    const int qrow = (blockIdx.x * 4 + wave) * 16 + col16;
    const int qcl = min(qrow, Lq - 1);

    v4h q_frag = *(const v4h*)(qh + ((size_t)bh * Lq + qcl) * 16 + grp * 4);
    const _Float16* kb = kh + (size_t)bh * Lk * 16;
    const _Float16* vb = vth + ((size_t)bh * 16 + col16) * Lkp;

    float m = -1e30f, l = 0.0f;
    v4f o_acc = {0.f, 0.f, 0.f, 0.f};

    for (int kc = 0; kc < Lk; kc += 64) {
        float s[16];
        bool full = (kc + 64 <= Lk);
        #pragma unroll
        for (int sub = 0; sub < 4; sub++) {
            int kr = min(kc + sub * 16 + col16, Lk - 1);
            v4h k_frag = *(const v4h*)(kb + (size_t)kr * 16 + grp * 4);
            v4f sf = __builtin_amdgcn_mfma_f32_16x16x16f16(
                         k_frag, q_frag, (v4f){0.f, 0.f, 0.f, 0.f}, 0, 0, 0);
            if (full) {
                #pragma unroll
                for (int r = 0; r < 4; r++) s[sub * 4 + r] = sf[r];
            } else {
                int key0 = kc + sub * 16 + grp * 4;
                #pragma unroll
                for (int r = 0; r < 4; r++)
                    s[sub * 4 + r] = (key0 + r < Lk) ? sf[r] : -1e30f;
            }
        }
        float mt = s[0];
        #pragma unroll
        for (int r = 1; r < 16; r++) mt = fmaxf(mt, s[r]);
        mt = fmaxf(mt, __shfl_xor(mt, 16, 64));
        mt = fmaxf(mt, __shfl_xor(mt, 32, 64));
        float mnew = fmaxf(m, mt);
        float corr = exp2f(m - mnew);
        float psum = 0.0f;
        _Float16 ph[16];
        #pragma unroll
        for (int r = 0; r < 16; r++) {
            float p = exp2f(s[r] - mnew);
            psum += p;
            ph[r] = (_Float16)p;
        }
        psum += __shfl_xor(psum, 16, 64);
        psum += __shfl_xor(psum, 32, 64);
        l = l * corr + psum;
        o_acc[0] *= corr; o_acc[1] *= corr; o_acc[2] *= corr; o_acc[3] *= corr;
        m = mnew;
        #pragma unroll
        for (int sub = 0; sub < 4; sub++) {
            v4h vt_frag = *(const v4h*)(vb + kc + sub * 16 + grp * 4);
            v4h p_frag = { ph[sub * 4 + 0], ph[sub * 4 + 1],
                           ph[sub * 4 + 2], ph[sub * 4 + 3] };
            o_acc = __builtin_amdgcn_mfma_f32_16x16x16f16(vt_frag, p_frag, o_acc, 0, 0, 0);
        }
    }

    if (qrow < Lq) {
        float inv = 1.0f / l;
        v4h ov = { (_Float16)(o_acc[0] * inv), (_Float16)(o_acc[1] * inv),
                   (_Float16)(o_acc[2] * inv), (_Float16)(o_acc[3] * inv) };
        *(v4h*)(outh + ((size_t)b * Lq + qrow) * DM + h * DH + grp * 4) = ov;
    }
}

// ---------------------------------------------------------------- residual + LayerNorm (in place on y, f16 shadow out)
__global__ __launch_bounds__(256) void add_ln_kernel(
    float* __restrict__ y, const float* __restrict__ res,
    const float* __restrict__ g, const float* __restrict__ bta,
    _Float16* __restrict__ yh, int M)
{
    int row = blockIdx.x * 4 + (threadIdx.x >> 6);
    int lane = threadIdx.x & 63;
    if (row >= M) return;
    float* yr = y + (size_t)row * DM;
    float x0 = yr[lane], x1 = yr[lane + 64];
    if (res) {
        const float* rr = res + (size_t)row * DM;
        x0 += rr[lane]; x1 += rr[lane + 64];
    }
    float sum = x0 + x1;
    #pragma unroll
    for (int off = 32; off > 0; off >>= 1) sum += __shfl_xor(sum, off, 64);
    float mean = sum * (1.0f / 128.0f);
    float d0 = x0 - mean, d1 = x1 - mean;
    float vs = d0 * d0 + d1 * d1;
    #pragma unroll
    for (int off = 32; off > 0; off >>= 1) vs += __shfl_xor(vs, off, 64);
    float rstd = rsqrtf(vs * (1.0f / 128.0f) + 1e-5f);
    float o0 = d0 * rstd * g[lane]      + bta[lane];
    float o1 = d1 * rstd * g[lane + 64] + bta[lane + 64];
    yr[lane] = o0; yr[lane + 64] = o1;
    _Float16* yhr = yh + (size_t)row * DM;
    yhr[lane] = (_Float16)o0; yhr[lane + 64] = (_Float16)o1;
}

// ---------------------------------------------------------------- final: out = tgt + eta * (y @ fc_w^T + fc_b)
__global__ __launch_bounds__(256) void final_kernel(
    const float* __restrict__ y, const float* __restrict__ tgt,
    const float* __restrict__ fcw, const float* __restrict__ fcb,
    float* __restrict__ out)
{
    int row = blockIdx.x * 4 + (threadIdx.x >> 6);
    int lane = threadIdx.x & 63;
    const float* yr = y + (size_t)row * DM;
    float a = yr[lane] * fcw[lane] + yr[lane + 64] * fcw[lane + 64];
    #pragma unroll
    for (int off = 32; off > 0; off >>= 1) a += __shfl_xor(a, off, 64);
    if (lane == 0) out[row] = tgt[row] + 1.0e-3f * (a + fcb[0]);
}

// ---------------------------------------------------------------- launcher
extern "C" void kernel_launch(void* const* d_in, const int* in_sizes, int n_in,
                              void* d_out, int out_size, void* d_ws, size_t ws_size,
                              hipStream_t stream)
{
    (void)in_sizes; (void)n_in; (void)out_size; (void)ws_size;
    const int*   src     = (const int*)  d_in[0];
    const float* tgt     = (const float*)d_in[1];
    const float* emb     = (const float*)d_in[2];
    const float* femb_w  = (const float*)d_in[3];
    const float* femb_b  = (const float*)d_in[4];
    const float* enc_inw = (const float*)d_in[5];
    const float* enc_inb = (const float*)d_in[6];
    const float* enc_ow  = (const float*)d_in[7];
    const float* enc_ob  = (const float*)d_in[8];
    const float* enc_l1g = (const float*)d_in[9];
    const float* enc_l1b = (const float*)d_in[10];
    const float* enc_l2g = (const float*)d_in[11];
    const float* enc_l2b = (const float*)d_in[12];
    const float* enc_f1w = (const float*)d_in[13];
    const float* enc_f1b = (const float*)d_in[14];
    const float* enc_f2w = (const float*)d_in[15];
    const float* enc_f2b = (const float*)d_in[16];
    const float* enc_ng  = (const float*)d_in[17];
    const float* enc_nb  = (const float*)d_in[18];
    const float* dec_inw = (const float*)d_in[19];
    const float* dec_inb = (const float*)d_in[20];
    const float* dec_ow  = (const float*)d_in[21];
    const float* dec_ob  = (const float*)d_in[22];
    const float* dec_cinw= (const float*)d_in[23];
    const float* dec_cinb= (const float*)d_in[24];
    const float* dec_cow = (const float*)d_in[25];
    const float* dec_cob = (const float*)d_in[26];
    const float* dec_l1g = (const float*)d_in[27];
    const float* dec_l1b = (const float*)d_in[28];
    const float* dec_l2g = (const float*)d_in[29];
    const float* dec_l2b = (const float*)d_in[30];
    const float* dec_l3g = (const float*)d_in[31];
    const float* dec_l3b = (const float*)d_in[32];
    const float* dec_f1w = (const float*)d_in[33];
    const float* dec_f1b = (const float*)d_in[34];
    const float* dec_f2w = (const float*)d_in[35];
    const float* dec_f2b = (const float*)d_in[36];
    const float* dec_ng  = (const float*)d_in[37];
    const float* dec_nb  = (const float*)d_in[38];
    const float* fc_w    = (const float*)d_in[39];
    const float* fc_b    = (const float*)d_in[40];

    // ---- workspace layout ----
    float* ws = (float*)d_ws;
    float* mem  = ws;                    // 51200 f32
    float* ybuf = ws + 51200;            // 1048576 f32
    float* tmp  = ws + 1099776;          // 1048576 f32
    _Float16* hb = (_Float16*)(ws + 2148352);
    _Float16* mem_h  = hb;               // 51200
    _Float16* ybuf_h = hb + 51200;       // 1048576
    _Float16* aout_h = hb + 1099776;     // 1048576
    _Float16* wh     = hb + 2148352;     // 2752512
    _Float16* arena  = hb + 4900864;     // 4194304
    _Float16* QH  = arena;               // up to 1048576
    _Float16* KH  = arena + 1048576;     // up to 1048576
    _Float16* VTH = arena + 2097152;     // up to 1048576
    _Float16* BIGH = arena;              // 4194304 (FFN hidden, reuses attn packs)

    const long W_ENC_INW = 0,       W_ENC_OW = 294912,  W_ENC_F1W = 393216,  W_ENC_F2W = 786432;
    const long W_DEC_INW = 1179648, W_DEC_OW = 1474560, W_DEC_CINW = 1572864, W_DEC_COW = 1867776;
    const long W_DEC_F1W = 1966080, W_DEC_F2W = 2359296;

    conv_w<<<dim3(384, 10), 256, 0, stream>>>(enc_inw, enc_ow, enc_f1w, enc_f2w,
                                              dec_inw, dec_ow, dec_cinw, dec_cow,
                                              dec_f1w, dec_f2w, wh);

    // ---------------- encoder (M = 400 rows) ----------------
    embed_src_kernel<<<200, 256, 0, stream>>>(src, emb, mem, mem_h);
    for (int i = 0; i < NL; i++) {
        gemm_h<2><<<dim3(4, 6), 256, 0, stream>>>(mem_h, wh + W_ENC_INW + i * 49152, enc_inb + i * 384,
            nullptr, nullptr, QH, KH, VTH, 400, 384, 128, 100, 128, 0, 0);
        attn_p<<<dim3(2, NH, B_), 256, 0, stream>>>(QH, KH, VTH, aout_h, 100, 100, 128);
        gemm_h<0><<<dim3(4, 2), 256, 0, stream>>>(aout_h, wh + W_ENC_OW + i * 16384, enc_ob + i * 128,
            tmp, nullptr, nullptr, nullptr, nullptr, 400, 128, 128, 0, 0, 0, 0);
        add_ln_kernel<<<100, 256, 0, stream>>>(mem, tmp, enc_l1g + i * 128, enc_l1b + i * 128, mem_h, 400);
        gemm_h<1><<<dim3(4, 8), 256, 0, stream>>>(mem_h, wh + W_ENC_F1W + i * 65536, enc_f1b + i * 512,
            nullptr, BIGH, nullptr, nullptr, nullptr, 400, 512, 128, 0, 0, 0, 0);
        gemm_h<0><<<dim3(4, 2), 256, 0, stream>>>(BIGH, wh + W_ENC_F2W + i * 65536, enc_f2b + i * 128,
            tmp, nullptr, nullptr, nullptr, nullptr, 400, 128, 512, 0, 0, 0, 0);
        add_ln_kernel<<<100, 256, 0, stream>>>(mem, tmp, enc_l2g + i * 128, enc_l2b + i * 128, mem_h, 400);
    }
    add_ln_kernel<<<100, 256, 0, stream>>>(mem, nullptr, enc_ng, enc_nb, mem_h, 400);

    // ---------------- decoder (M = 8192 rows) ----------------
    embed_tgt_kernel<<<4096, 256, 0, stream>>>(tgt, femb_w, femb_b, ybuf, ybuf_h);
    for (int i = 0; i < NL; i++) {
        // self-attention
        gemm_h<2><<<dim3(64, 6), 256, 0, stream>>>(ybuf_h, wh + W_DEC_INW + i * 49152, dec_inb + i * 384,
            nullptr, nullptr, QH, KH, VTH, 8192, 384, 128, 2048, 2048, 0, 11);
        attn_p<<<dim3(32, NH, B_), 256, 0, stream>>>(QH, KH, VTH, aout_h, 2048, 2048, 2048);
        gemm_h<0><<<dim3(64, 2), 256, 0, stream>>>(aout_h, wh + W_DEC_OW + i * 16384, dec_ob + i * 128,
            tmp, nullptr, nullptr, nullptr, nullptr, 8192, 128, 128, 0, 0, 0, 0);
        add_ln_kernel<<<2048, 256, 0, stream>>>(ybuf, tmp, dec_l1g + i * 128, dec_l1b + i * 128, ybuf_h, 8192);
        // cross-attention
        gemm_h<2><<<dim3(64, 2), 256, 0, stream>>>(ybuf_h, wh + W_DEC_CINW + i * 49152, dec_cinb + i * 384,
            nullptr, nullptr, QH, nullptr, nullptr, 8192, 128, 128, 2048, 2048, 0, 11);
        gemm_h<2><<<dim3(4, 4), 256, 0, stream>>>(mem_h, wh + W_DEC_CINW + i * 49152 + 16384, dec_cinb + i * 384 + 128,
            nullptr, nullptr, nullptr, KH, VTH, 400, 256, 128, 100, 128, 128, 0);
        attn_p<<<dim3(32, NH, B_), 256, 0, stream>>>(QH, KH, VTH, aout_h, 2048, 100, 128);
        gemm_h<0><<<dim3(64, 2), 256, 0, stream>>>(aout_h, wh + W_DEC_COW + i * 16384, dec_cob + i * 128,
            tmp, nullptr, nullptr, nullptr, nullptr, 8192, 128, 128, 0, 0, 0, 0);
        add_ln_kernel<<<2048, 256, 0, stream>>>(ybuf, tmp, dec_l2g + i * 128, dec_l2b + i * 128, ybuf_h, 8192);
        // FFN
        gemm_h<1><<<dim3(64, 8), 256, 0, stream>>>(ybuf_h, wh + W_DEC_F1W + i * 65536, dec_f1b + i * 512,
            nullptr, BIGH, nullptr, nullptr, nullptr, 8192, 512, 128, 0, 0, 0, 0);
        gemm_h<0><<<dim3(64, 2), 256, 0, stream>>>(BIGH, wh + W_DEC_F2W + i * 65536, dec_f2b + i * 128,
            tmp, nullptr, nullptr, nullptr, nullptr, 8192, 128, 512, 0, 0, 0, 0);
        add_ln_kernel<<<2048, 256, 0, stream>>>(ybuf, tmp, dec_l3g + i * 128, dec_l3b + i * 128, ybuf_h, 8192);
    }
    add_ln_kernel<<<2048, 256, 0, stream>>>(ybuf, nullptr, dec_ng, dec_nb, ybuf_h, 8192);
    final_kernel<<<2048, 256, 0, stream>>>(ybuf, tgt, fc_w, fc_b, (float*)d_out);
}

// Round 4
// 1205.208 us; speedup vs baseline: 3.3433x; 1.2675x over previous
//
#include <hip/hip_runtime.h>
#include <hip/hip_bf16.h>
#include <math.h>

#define B_ 4
#define S_ 100
#define T_ 2048
#define DM 128
#define NH 8
#define DH 16
#define NL 6
#define DFFN 512

#define SQRT_D 11.313708498984761f   // sqrt(128)
#define LN10K  9.210340371976184f    // ln(10000)
#define QSCALE 0.36067376022224085f  // 0.25 * log2(e)  (softmax in exp2 domain)

typedef _Float16 v4h __attribute__((ext_vector_type(4)));
typedef float    v4f __attribute__((ext_vector_type(4)));

__device__ __forceinline__ float fexp2(float x) { return __builtin_amdgcn_exp2f(x); }

// ---------------------------------------------------------------- posenc
__device__ __forceinline__ float pe_val(int pos, int d) {
    int i = d >> 1;
    float dv = __expf((float)i * (-2.0f * LN10K / 128.0f));
    float ang = (float)pos * dv;
    return (d & 1) ? __cosf(ang) : __sinf(ang);
}

// ---------------------------------------------------------------- weight f32->f16 conversion (once per call)
__global__ __launch_bounds__(256) void conv_w(
    const float* __restrict__ p0, const float* __restrict__ p1,
    const float* __restrict__ p2, const float* __restrict__ p3,
    const float* __restrict__ p4, const float* __restrict__ p5,
    const float* __restrict__ p6, const float* __restrict__ p7,
    const float* __restrict__ p8, const float* __restrict__ p9,
    _Float16* __restrict__ out)
{
    int seg = blockIdx.y;
    const float* s; int sz; long off;
    switch (seg) {
        case 0: s = p0; sz = 294912; off = 0;       break;
        case 1: s = p1; sz = 98304;  off = 294912;  break;
        case 2: s = p2; sz = 393216; off = 393216;  break;
        case 3: s = p3; sz = 393216; off = 786432;  break;
        case 4: s = p4; sz = 294912; off = 1179648; break;
        case 5: s = p5; sz = 98304;  off = 1474560; break;
        case 6: s = p6; sz = 294912; off = 1572864; break;
        case 7: s = p7; sz = 98304;  off = 1867776; break;
        case 8: s = p8; sz = 393216; off = 1966080; break;
        default: s = p9; sz = 393216; off = 2359296; break;
    }
    int idx = (blockIdx.x * 256 + threadIdx.x) * 4;
    if (idx >= sz) return;
    float4 v = *(const float4*)(s + idx);
    v4h h = { (_Float16)v.x, (_Float16)v.y, (_Float16)v.z, (_Float16)v.w };
    *(v4h*)(out + off + idx) = h;
}

// ---------------------------------------------------------------- embeds (write f32 + f16 shadow)
__global__ __launch_bounds__(256) void embed_src_kernel(
    const int* __restrict__ src, const float* __restrict__ emb,
    float* __restrict__ out, _Float16* __restrict__ outh)
{
    int idx = blockIdx.x * 256 + threadIdx.x;
    if (idx >= B_ * S_ * DM) return;
    int d = idx & 127;
    int row = idx >> 7;
    int b = row / S_;
    int tok = src[row];
    float v = emb[tok * DM + d] * SQRT_D + pe_val(b, d);
    out[idx] = v;
    outh[idx] = (_Float16)v;
}

__global__ __launch_bounds__(256) void embed_tgt_kernel(
    const float* __restrict__ tgt, const float* __restrict__ fw,
    const float* __restrict__ fb, float* __restrict__ out, _Float16* __restrict__ outh)
{
    int idx = blockIdx.x * 256 + threadIdx.x;
    if (idx >= B_ * T_ * DM) return;
    int d = idx & 127;
    int row = idx >> 7;
    int b = row >> 11;
    float v = (tgt[row] * fw[d] + fb[d]) * SQRT_D + pe_val(b, d);
    out[idx] = v;
    outh[idx] = (_Float16)v;
}

// ---------------------------------------------------------------- f16 MFMA GEMM (NT), BM=128 BN=64 BK=64, 256 thr
// MODE 1: f16 C + relu. MODE 2: attention pack (q scaled, k, v-transposed).
template<int MODE>
__global__ __launch_bounds__(256) void gemm_h(
    const _Float16* __restrict__ A, const _Float16* __restrict__ W,
    const float* __restrict__ bias,
    _Float16* __restrict__ Ch,
    _Float16* __restrict__ qo, _Float16* __restrict__ ko, _Float16* __restrict__ vo,
    int M, int N, int K, int L, int Lkp, int part_off, int Lshift)
{
    __shared__ _Float16 As[128][72];
    __shared__ _Float16 Ws[64][72];
    const int t = threadIdx.x;
    const int wave = t >> 6, lane = t & 63;
    const int col16 = lane & 15, grp = lane >> 4;
    const int row0 = blockIdx.x * 128, col0 = blockIdx.y * 64;
    const int wrow0 = (wave >> 1) * 64, wcol0 = (wave & 1) * 32;

    v4f acc[4][2];
    #pragma unroll
    for (int m = 0; m < 4; m++)
        #pragma unroll
        for (int n = 0; n < 2; n++) acc[m][n] = (v4f){0.f, 0.f, 0.f, 0.f};

    for (int k0 = 0; k0 < K; k0 += 64) {
        #pragma unroll
        for (int i = 0; i < 4; i++) {
            int id = i * 256 + t;
            int r = id >> 3, j = id & 7;
            int gr = min(row0 + r, M - 1);
            int4 v = *(const int4*)(A + (size_t)gr * K + k0 + j * 8);
            *(int4*)&As[r][j * 8] = v;
        }
        #pragma unroll
        for (int i = 0; i < 2; i++) {
            int id = i * 256 + t;
            int r = id >> 3, j = id & 7;
            int4 v = *(const int4*)(W + (size_t)(col0 + r) * K + k0 + j * 8);
            *(int4*)&Ws[r][j * 8] = v;
        }
        __syncthreads();
        #pragma unroll
        for (int kk = 0; kk < 4; kk++) {
            v4h a[4], bf[2];
            #pragma unroll
            for (int m = 0; m < 4; m++)
                a[m] = *(const v4h*)&As[wrow0 + m * 16 + col16][kk * 16 + grp * 4];
            #pragma unroll
            for (int n = 0; n < 2; n++)
                bf[n] = *(const v4h*)&Ws[wcol0 + n * 16 + col16][kk * 16 + grp * 4];
            #pragma unroll
            for (int m = 0; m < 4; m++)
                #pragma unroll
                for (int n = 0; n < 2; n++)
                    acc[m][n] = __builtin_amdgcn_mfma_f32_16x16x16f16(a[m], bf[n], acc[m][n], 0, 0, 0);
        }
        __syncthreads();
    }

    #pragma unroll
    for (int n = 0; n < 2; n++) {
        int gcol = col0 + wcol0 + n * 16 + col16;
        float bv = bias[gcol];
        #pragma unroll
        for (int m = 0; m < 4; m++) {
            int rbase = row0 + wrow0 + m * 16 + grp * 4;
            #pragma unroll
            for (int r = 0; r < 4; r++) {
                int grow = rbase + r;
                if (grow >= M) continue;
                float v = acc[m][n][r] + bv;
                if (MODE == 1) {
                    Ch[(size_t)grow * N + gcol] = (_Float16)fmaxf(v, 0.f);
                } else {
                    int pc = gcol + part_off;
                    int part = pc >> 7;
                    int h = (pc >> 4) & 7;
                    int d = pc & 15;
                    int b = Lshift ? (grow >> Lshift) : (grow / L);
                    int pos = grow - b * L;
                    int bh = b * NH + h;
                    if (part == 0)
                        qo[((size_t)bh * L + pos) * 16 + d] = (_Float16)(v * QSCALE);
                    else if (part == 1)
                        ko[((size_t)bh * L + pos) * 16 + d] = (_Float16)v;
                    else
                        vo[((size_t)bh * 16 + d) * Lkp + pos] = (_Float16)v;
                }
            }
        }
    }
}

// ---------------------------------------------------------------- fused GEMM(N=128) + residual + LayerNorm
// C = A[M,K] @ W[128,K]^T + bias; y = LN(res + C)*g + b -> yout (f32) + youth (f16)
// BM=32, 128 threads = 2 waves, wave = 16 rows x 128 cols (acc[8]).
__global__ __launch_bounds__(128) void gemm_ln(
    const _Float16* __restrict__ A, const _Float16* __restrict__ W,
    const float* __restrict__ bias, const float* __restrict__ res,
    const float* __restrict__ g, const float* __restrict__ bt,
    float* __restrict__ yout, _Float16* __restrict__ youth, int M, int K)
{
    __shared__ _Float16 As[32][72];
    __shared__ _Float16 Ws[128][72];
    const int t = threadIdx.x;
    const int wave = t >> 6, lane = t & 63;
    const int col16 = lane & 15, grp = lane >> 4;
    const int row0 = blockIdx.x * 32;

    v4f acc[8];
    #pragma unroll
    for (int n = 0; n < 8; n++) acc[n] = (v4f){0.f, 0.f, 0.f, 0.f};

    for (int k0 = 0; k0 < K; k0 += 64) {
        #pragma unroll
        for (int i = 0; i < 2; i++) {
            int id = i * 128 + t;            // 0..255
            int r = id >> 3, j = id & 7;
            int gr = min(row0 + r, M - 1);
            int4 v = *(const int4*)(A + (size_t)gr * K + k0 + j * 8);
            *(int4*)&As[r][j * 8] = v;
        }
        #pragma unroll
        for (int i = 0; i < 8; i++) {
            int id = i * 128 + t;            // 0..1023
            int r = id >> 3, j = id & 7;
            int4 v = *(const int4*)(W + (size_t)r * K + k0 + j * 8);
            *(int4*)&Ws[r][j * 8] = v;
        }
        __syncthreads();
        #pragma unroll
        for (int kk = 0; kk < 4; kk++) {
            v4h a = *(const v4h*)&As[wave * 16 + col16][kk * 16 + grp * 4];
            #pragma unroll
            for (int n = 0; n < 8; n++) {
                v4h bf = *(const v4h*)&Ws[n * 16 + col16][kk * 16 + grp * 4];
                acc[n] = __builtin_amdgcn_mfma_f32_16x16x16f16(a, bf, acc[n], 0, 0, 0);
            }
        }
        __syncthreads();
    }

    float bv[8], gv[8], btv[8];
    #pragma unroll
    for (int n = 0; n < 8; n++) {
        bv[n]  = bias[col16 + 16 * n];
        gv[n]  = g[col16 + 16 * n];
        btv[n] = bt[col16 + 16 * n];
    }
    #pragma unroll
    for (int r = 0; r < 4; r++) {
        int row = row0 + wave * 16 + grp * 4 + r;
        if (row < M) {
            float x[8];
            float sum = 0.f;
            #pragma unroll
            for (int n = 0; n < 8; n++) {
                x[n] = acc[n][r] + bv[n] + res[(size_t)row * DM + col16 + 16 * n];
                sum += x[n];
            }
            sum += __shfl_xor(sum, 1, 64);
            sum += __shfl_xor(sum, 2, 64);
            sum += __shfl_xor(sum, 4, 64);
            sum += __shfl_xor(sum, 8, 64);
            float mean = sum * (1.0f / 128.0f);
            float vs = 0.f;
            #pragma unroll
            for (int n = 0; n < 8; n++) {
                x[n] -= mean;
                vs += x[n] * x[n];
            }
            vs += __shfl_xor(vs, 1, 64);
            vs += __shfl_xor(vs, 2, 64);
            vs += __shfl_xor(vs, 4, 64);
            vs += __shfl_xor(vs, 8, 64);
            float rstd = rsqrtf(vs * (1.0f / 128.0f) + 1e-5f);
            #pragma unroll
            for (int n = 0; n < 8; n++) {
                float o = x[n] * rstd * gv[n] + btv[n];
                yout[(size_t)row * DM + col16 + 16 * n] = o;
                youth[(size_t)row * DM + col16 + 16 * n] = (_Float16)o;
            }
        }
    }
}

// ---------------------------------------------------------------- MFMA flash attention v2: defer-max, per-lane l, split-KV
// qh: [B,H,Lq,16] (scaled by QSCALE), kh: [B,H,Lk,16], vth: [B,H,16,Lkp]
// FINAL=1: write normalized f16 rows into outh [B*Lq,128].
// FINAL=0: write normalized partials po (f16) + pm/pl, indexed by zb=b*NS+split.
// grid: (ceil(Lq/64), H, B*NS), 256 thr = 4 waves, wave owns 16 q-rows.
template<int FINAL>
__global__ __launch_bounds__(256, 6) void attn_p2(
    const _Float16* __restrict__ qh, const _Float16* __restrict__ kh,
    const _Float16* __restrict__ vth, _Float16* __restrict__ outh,
    _Float16* __restrict__ po, float* __restrict__ pm, float* __restrict__ pl,
    int Lq, int Lk, int Lkp, int NS)
{
    const int zb = blockIdx.z;
    const int b = zb / NS, split = zb - b * NS;
    const int h = blockIdx.y;
    const int wave = threadIdx.x >> 6, lane = threadIdx.x & 63;
    const int col16 = lane & 15, grp = lane >> 4;
    const int bh = b * NH + h;
    const int qrow = (blockIdx.x * 4 + wave) * 16 + col16;
    const int qcl = min(qrow, Lq - 1);

    v4h q_frag = *(const v4h*)(qh + ((size_t)bh * Lq + qcl) * 16 + grp * 4);
    const _Float16* kb = kh + (size_t)bh * Lk * 16;
    const _Float16* vb = vth + ((size_t)bh * 16 + col16) * Lkp;

    const int kvLen = Lk / NS;
    const int kv0 = split * kvLen;
    const int kvEnd = kv0 + kvLen;

    float m = -1e30f, l = 0.0f;
    v4f o_acc = {0.f, 0.f, 0.f, 0.f};

    for (int kc = kv0; kc < kvEnd; kc += 64) {
        v4f s4[4];
        bool full = (kc + 64 <= kvEnd);
        #pragma unroll
        for (int sub = 0; sub < 4; sub++) {
            int kr = min(kc + sub * 16 + col16, Lk - 1);
            v4h k_frag = *(const v4h*)(kb + (size_t)kr * 16 + grp * 4);
            s4[sub] = __builtin_amdgcn_mfma_f32_16x16x16f16(
                          k_frag, q_frag, (v4f){0.f, 0.f, 0.f, 0.f}, 0, 0, 0);
        }
        if (!full) {
            #pragma unroll
            for (int sub = 0; sub < 4; sub++)
                #pragma unroll
                for (int r = 0; r < 4; r++) {
                    int key = kc + sub * 16 + grp * 4 + r;
                    if (key >= kvEnd) s4[sub][r] = -1e30f;
                }
        }
        // chunk-local max (tree)
        float c0 = fmaxf(fmaxf(s4[0][0], s4[0][1]), fmaxf(s4[0][2], s4[0][3]));
        float c1 = fmaxf(fmaxf(s4[1][0], s4[1][1]), fmaxf(s4[1][2], s4[1][3]));
        float c2 = fmaxf(fmaxf(s4[2][0], s4[2][1]), fmaxf(s4[2][2], s4[2][3]));
        float c3 = fmaxf(fmaxf(s4[3][0], s4[3][1]), fmaxf(s4[3][2], s4[3][3]));
        float cm = fmaxf(fmaxf(c0, c1), fmaxf(c2, c3));
        if (__any(cm > m + 8.0f)) {           // defer-max: rare wave-uniform path
            float nm = fmaxf(cm, m);
            nm = fmaxf(nm, __shfl_xor(nm, 16, 64));
            nm = fmaxf(nm, __shfl_xor(nm, 32, 64));
            float corr = fexp2(m - nm);
            l *= corr;
            o_acc[0] *= corr; o_acc[1] *= corr; o_acc[2] *= corr; o_acc[3] *= corr;
            m = nm;
        }
        v4h ph[4];
        #pragma unroll
        for (int sub = 0; sub < 4; sub++)
            #pragma unroll
            for (int r = 0; r < 4; r++) {
                float p = fexp2(s4[sub][r] - m);   // bounded by 2^8
                l += p;
                ph[sub][r] = (_Float16)p;
            }
        #pragma unroll
        for (int sub = 0; sub < 4; sub++) {
            v4h vt_frag = *(const v4h*)(vb + kc + sub * 16 + grp * 4);
            o_acc = __builtin_amdgcn_mfma_f32_16x16x16f16(vt_frag, ph[sub], o_acc, 0, 0, 0);
        }
    }

    l += __shfl_xor(l, 16, 64);
    l += __shfl_xor(l, 32, 64);
    float inv = 1.0f / l;
    if (qrow < Lq) {
        v4h ov = { (_Float16)(o_acc[0] * inv), (_Float16)(o_acc[1] * inv),
                   (_Float16)(o_acc[2] * inv), (_Float16)(o_acc[3] * inv) };
        if (FINAL) {
            *(v4h*)(outh + ((size_t)b * Lq + qrow) * DM + h * DH + grp * 4) = ov;
        } else {
            size_t pidx = ((size_t)zb * NH + h) * Lq + qrow;
            *(v4h*)(po + pidx * 16 + grp * 4) = ov;
            if (grp == 0) { pm[pidx] = m; pl[pidx] = l; }
        }
    }
}

// ---------------------------------------------------------------- merge NS=2 partials -> aout_h
__global__ __launch_bounds__(256) void attn_merge(
    const _Float16* __restrict__ po, const float* __restrict__ pm,
    const float* __restrict__ pl, _Float16* __restrict__ outh)
{
    int t = blockIdx.x * 256 + threadIdx.x;   // 4*2048*8*4 total
    int di = t & 3;
    int h = (t >> 2) & 7;
    int q = (t >> 5) & 2047;
    int b = t >> 16;
    size_t i0 = ((size_t)(b * 2 + 0) * NH + h) * T_ + q;
    size_t i1 = ((size_t)(b * 2 + 1) * NH + h) * T_ + q;
    float m0 = pm[i0], m1 = pm[i1];
    float M = fmaxf(m0, m1);
    float w0 = fexp2(m0 - M) * pl[i0];
    float w1 = fexp2(m1 - M) * pl[i1];
    float inv = 1.0f / (w0 + w1);
    w0 *= inv; w1 *= inv;
    v4h o0 = *(const v4h*)(po + i0 * 16 + di * 4);
    v4h o1 = *(const v4h*)(po + i1 * 16 + di * 4);
    v4h ov;
    #pragma unroll
    for (int r = 0; r < 4; r++)
        ov[r] = (_Float16)((float)o0[r] * w0 + (float)o1[r] * w1);
    *(v4h*)(outh + ((size_t)b * T_ + q) * DM + h * DH + di * 4) = ov;
}

// ---------------------------------------------------------------- residual + LayerNorm (standalone, for final norms)
__global__ __launch_bounds__(256) void add_ln_kernel(
    float* __restrict__ y, const float* __restrict__ res,
    const float* __restrict__ g, const float* __restrict__ bta,
    _Float16* __restrict__ yh, int M)
{
    int row = blockIdx.x * 4 + (threadIdx.x >> 6);
    int lane = threadIdx.x & 63;
    if (row >= M) return;
    float* yr = y + (size_t)row * DM;
    float x0 = yr[lane], x1 = yr[lane + 64];
    if (res) {
        const float* rr = res + (size_t)row * DM;
        x0 += rr[lane]; x1 += rr[lane + 64];
    }
    float sum = x0 + x1;
    #pragma unroll
    for (int off = 32; off > 0; off >>= 1) sum += __shfl_xor(sum, off, 64);
    float mean = sum * (1.0f / 128.0f);
    float d0 = x0 - mean, d1 = x1 - mean;
    float vs = d0 * d0 + d1 * d1;
    #pragma unroll
    for (int off = 32; off > 0; off >>= 1) vs += __shfl_xor(vs, off, 64);
    float rstd = rsqrtf(vs * (1.0f / 128.0f) + 1e-5f);
    float o0 = d0 * rstd * g[lane]      + bta[lane];
    float o1 = d1 * rstd * g[lane + 64] + bta[lane + 64];
    yr[lane] = o0; yr[lane + 64] = o1;
    _Float16* yhr = yh + (size_t)row * DM;
    yhr[lane] = (_Float16)o0; yhr[lane + 64] = (_Float16)o1;
}

// ---------------------------------------------------------------- final: out = tgt + eta * (y @ fc_w^T + fc_b)
__global__ __launch_bounds__(256) void final_kernel(
    const float* __restrict__ y, const float* __restrict__ tgt,
    const float* __restrict__ fcw, const float* __restrict__ fcb,
    float* __restrict__ out)
{
    int row = blockIdx.x * 4 + (threadIdx.x >> 6);
    int lane = threadIdx.x & 63;
    const float* yr = y + (size_t)row * DM;
    float a = yr[lane] * fcw[lane] + yr[lane + 64] * fcw[lane + 64];
    #pragma unroll
    for (int off = 32; off > 0; off >>= 1) a += __shfl_xor(a, off, 64);
    if (lane == 0) out[row] = tgt[row] + 1.0e-3f * (a + fcb[0]);
}

// ---------------------------------------------------------------- launcher
extern "C" void kernel_launch(void* const* d_in, const int* in_sizes, int n_in,
                              void* d_out, int out_size, void* d_ws, size_t ws_size,
                              hipStream_t stream)
{
    (void)in_sizes; (void)n_in; (void)out_size; (void)ws_size;
    const int*   src     = (const int*)  d_in[0];
    const float* tgt     = (const float*)d_in[1];
    const float* emb     = (const float*)d_in[2];
    const float* femb_w  = (const float*)d_in[3];
    const float* femb_b  = (const float*)d_in[4];
    const float* enc_inw = (const float*)d_in[5];
    const float* enc_inb = (const float*)d_in[6];
    const float* enc_ow  = (const float*)d_in[7];
    const float* enc_ob  = (const float*)d_in[8];
    const float* enc_l1g = (const float*)d_in[9];
    const float* enc_l1b = (const float*)d_in[10];
    const float* enc_l2g = (const float*)d_in[11];
    const float* enc_l2b = (const float*)d_in[12];
    const float* enc_f1w = (const float*)d_in[13];
    const float* enc_f1b = (const float*)d_in[14];
    const float* enc_f2w = (const float*)d_in[15];
    const float* enc_f2b = (const float*)d_in[16];
    const float* enc_ng  = (const float*)d_in[17];
    const float* enc_nb  = (const float*)d_in[18];
    const float* dec_inw = (const float*)d_in[19];
    const float* dec_inb = (const float*)d_in[20];
    const float* dec_ow  = (const float*)d_in[21];
    const float* dec_ob  = (const float*)d_in[22];
    const float* dec_cinw= (const float*)d_in[23];
    const float* dec_cinb= (const float*)d_in[24];
    const float* dec_cow = (const float*)d_in[25];
    const float* dec_cob = (const float*)d_in[26];
    const float* dec_l1g = (const float*)d_in[27];
    const float* dec_l1b = (const float*)d_in[28];
    const float* dec_l2g = (const float*)d_in[29];
    const float* dec_l2b = (const float*)d_in[30];
    const float* dec_l3g = (const float*)d_in[31];
    const float* dec_l3b = (const float*)d_in[32];
    const float* dec_f1w = (const float*)d_in[33];
    const float* dec_f1b = (const float*)d_in[34];
    const float* dec_f2w = (const float*)d_in[35];
    const float* dec_f2b = (const float*)d_in[36];
    const float* dec_ng  = (const float*)d_in[37];
    const float* dec_nb  = (const float*)d_in[38];
    const float* fc_w    = (const float*)d_in[39];
    const float* fc_b    = (const float*)d_in[40];

    // ---- workspace layout ----
    float* ws = (float*)d_ws;
    float* mem  = ws;                        // 51200
    float* ybuf = ws + 51200;                // 1048576
    float* pm   = ws + 51200 + 1048576;      // 131072  (2*4*8*2048)
    float* pl   = pm + 131072;               // 131072
    _Float16* hb = (_Float16*)(pl + 131072);
    _Float16* mem_h  = hb;                   // 51200
    _Float16* ybuf_h = hb + 51200;           // 1048576
    _Float16* aout_h = hb + 1099776;         // 1048576
    _Float16* wh     = hb + 2148352;         // 2752512
    _Float16* po     = hb + 4900864;         // 2097152 (normalized f16 partials)
    _Float16* arena  = hb + 6998016;         // 4194304
    _Float16* QH  = arena;
    _Float16* KH  = arena + 1048576;
    _Float16* VTH = arena + 2097152;
    _Float16* BIGH = arena;                  // FFN hidden reuses attn packs

    const long W_ENC_INW = 0,       W_ENC_OW = 294912,  W_ENC_F1W = 393216,  W_ENC_F2W = 786432;
    const long W_DEC_INW = 1179648, W_DEC_OW = 1474560, W_DEC_CINW = 1572864, W_DEC_COW = 1867776;
    const long W_DEC_F1W = 1966080, W_DEC_F2W = 2359296;

    conv_w<<<dim3(384, 10), 256, 0, stream>>>(enc_inw, enc_ow, enc_f1w, enc_f2w,
                                              dec_inw, dec_ow, dec_cinw, dec_cow,
                                              dec_f1w, dec_f2w, wh);

    // ---------------- encoder (M = 400 rows) ----------------
    embed_src_kernel<<<200, 256, 0, stream>>>(src, emb, mem, mem_h);
    for (int i = 0; i < NL; i++) {
        gemm_h<2><<<dim3(4, 6), 256, 0, stream>>>(mem_h, wh + W_ENC_INW + i * 49152, enc_inb + i * 384,
            nullptr, QH, KH, VTH, 400, 384, 128, 100, 128, 0, 0);
        attn_p2<1><<<dim3(2, NH, B_), 256, 0, stream>>>(QH, KH, VTH, aout_h,
            nullptr, nullptr, nullptr, 100, 100, 128, 1);
        gemm_ln<<<13, 128, 0, stream>>>(aout_h, wh + W_ENC_OW + i * 16384, enc_ob + i * 128,
            mem, enc_l1g + i * 128, enc_l1b + i * 128, mem, mem_h, 400, 128);
        gemm_h<1><<<dim3(4, 8), 256, 0, stream>>>(mem_h, wh + W_ENC_F1W + i * 65536, enc_f1b + i * 512,
            BIGH, nullptr, nullptr, nullptr, 400, 512, 128, 0, 0, 0, 0);
        gemm_ln<<<13, 128, 0, stream>>>(BIGH, wh + W_ENC_F2W + i * 65536, enc_f2b + i * 128,
            mem, enc_l2g + i * 128, enc_l2b + i * 128, mem, mem_h, 400, 512);
    }
    add_ln_kernel<<<100, 256, 0, stream>>>(mem, nullptr, enc_ng, enc_nb, mem_h, 400);

    // ---------------- decoder (M = 8192 rows) ----------------
    embed_tgt_kernel<<<4096, 256, 0, stream>>>(tgt, femb_w, femb_b, ybuf, ybuf_h);
    for (int i = 0; i < NL; i++) {
        // self-attention (split-KV x2)
        gemm_h<2><<<dim3(64, 6), 256, 0, stream>>>(ybuf_h, wh + W_DEC_INW + i * 49152, dec_inb + i * 384,
            nullptr, QH, KH, VTH, 8192, 384, 128, 2048, 2048, 0, 11);
        attn_p2<0><<<dim3(32, NH, B_ * 2), 256, 0, stream>>>(QH, KH, VTH, nullptr,
            po, pm, pl, 2048, 2048, 2048, 2);
        attn_merge<<<1024, 256, 0, stream>>>(po, pm, pl, aout_h);
        gemm_ln<<<256, 128, 0, stream>>>(aout_h, wh + W_DEC_OW + i * 16384, dec_ob + i * 128,
            ybuf, dec_l1g + i * 128, dec_l1b + i * 128, ybuf, ybuf_h, 8192, 128);
        // cross-attention
        gemm_h<2><<<dim3(64, 2), 256, 0, stream>>>(ybuf_h, wh + W_DEC_CINW + i * 49152, dec_cinb + i * 384,
            nullptr, QH, nullptr, nullptr, 8192, 128, 128, 2048, 2048, 0, 11);
        gemm_h<2><<<dim3(4, 4), 256, 0, stream>>>(mem_h, wh + W_DEC_CINW + i * 49152 + 16384, dec_cinb + i * 384 + 128,
            nullptr, nullptr, KH, VTH, 400, 256, 128, 100, 128, 128, 0);
        attn_p2<1><<<dim3(32, NH, B_), 256, 0, stream>>>(QH, KH, VTH, aout_h,
            nullptr, nullptr, nullptr, 2048, 100, 128, 1);
        gemm_ln<<<256, 128, 0, stream>>>(aout_h, wh + W_DEC_COW + i * 16384, dec_cob + i * 128,
            ybuf, dec_l2g + i * 128, dec_l2b + i * 128, ybuf, ybuf_h, 8192, 128);
        // FFN
        gemm_h<1><<<dim3(64, 8), 256, 0, stream>>>(ybuf_h, wh + W_DEC_F1W + i * 65536, dec_f1b + i * 512,
            BIGH, nullptr, nullptr, nullptr, 8192, 512, 128, 0, 0, 0, 0);
        gemm_ln<<<256, 128, 0, stream>>>(BIGH, wh + W_DEC_F2W + i * 65536, dec_f2b + i * 128,
            ybuf, dec_l3g + i * 128, dec_l3b + i * 128, ybuf, ybuf_h, 8192, 512);
    }
    add_ln_kernel<<<2048, 256, 0, stream>>>(ybuf, nullptr, dec_ng, dec_nb, ybuf_h, 8192);
    final_kernel<<<2048, 256, 0, stream>>>(ybuf, tgt, fc_w, fc_b, (float*)d_out);
}

// Round 6
// 946.698 us; speedup vs baseline: 4.2563x; 1.2731x over previous
//
#include <hip/hip_runtime.h>
#include <hip/hip_bf16.h>
#include <math.h>

#define B_ 4
#define S_ 100
#define T_ 2048
#define DM 128
#define NH 8
#define DH 16
#define NL 6
#define DFFN 512

#define SQRT_D 11.313708498984761f   // sqrt(128)
#define LN10K  9.210340371976184f    // ln(10000)
#define QSCALE 0.36067376022224085f  // 0.25 * log2(e)  (softmax in exp2 domain)

typedef _Float16 v4h __attribute__((ext_vector_type(4)));
typedef _Float16 v8h __attribute__((ext_vector_type(8)));
typedef float    v4f __attribute__((ext_vector_type(4)));

__device__ __forceinline__ float fexp2(float x) { return __builtin_amdgcn_exp2f(x); }

__device__ __forceinline__ void gload_lds16(const void* g, void* l) {
    __builtin_amdgcn_global_load_lds(
        (const __attribute__((address_space(1))) unsigned int*)g,
        (__attribute__((address_space(3))) unsigned int*)l, 16, 0, 0);
}

// ---------------------------------------------------------------- posenc
__device__ __forceinline__ float pe_val(int pos, int d) {
    int i = d >> 1;
    float dv = __expf((float)i * (-2.0f * LN10K / 128.0f));
    float ang = (float)pos * dv;
    return (d & 1) ? __cosf(ang) : __sinf(ang);
}

// ---------------------------------------------------------------- weight f32->f16 conversion (once per call)
__global__ __launch_bounds__(256) void conv_w(
    const float* __restrict__ p0, const float* __restrict__ p1,
    const float* __restrict__ p2, const float* __restrict__ p3,
    const float* __restrict__ p4, const float* __restrict__ p5,
    const float* __restrict__ p6, const float* __restrict__ p7,
    const float* __restrict__ p8, const float* __restrict__ p9,
    _Float16* __restrict__ out)
{
    int seg = blockIdx.y;
    const float* s; int sz; long off;
    switch (seg) {
        case 0: s = p0; sz = 294912; off = 0;       break;
        case 1: s = p1; sz = 98304;  off = 294912;  break;
        case 2: s = p2; sz = 393216; off = 393216;  break;
        case 3: s = p3; sz = 393216; off = 786432;  break;
        case 4: s = p4; sz = 294912; off = 1179648; break;
        case 5: s = p5; sz = 98304;  off = 1474560; break;
        case 6: s = p6; sz = 294912; off = 1572864; break;
        case 7: s = p7; sz = 98304;  off = 1867776; break;
        case 8: s = p8; sz = 393216; off = 1966080; break;
        default: s = p9; sz = 393216; off = 2359296; break;
    }
    int idx = (blockIdx.x * 256 + threadIdx.x) * 4;
    if (idx >= sz) return;
    float4 v = *(const float4*)(s + idx);
    v4h h = { (_Float16)v.x, (_Float16)v.y, (_Float16)v.z, (_Float16)v.w };
    *(v4h*)(out + off + idx) = h;
}

// ---------------------------------------------------------------- embeds (write f32 + f16 shadow)
__global__ __launch_bounds__(256) void embed_src_kernel(
    const int* __restrict__ src, const float* __restrict__ emb,
    float* __restrict__ out, _Float16* __restrict__ outh)
{
    int idx = blockIdx.x * 256 + threadIdx.x;
    if (idx >= B_ * S_ * DM) return;
    int d = idx & 127;
    int row = idx >> 7;
    int b = row / S_;
    int tok = src[row];
    float v = emb[tok * DM + d] * SQRT_D + pe_val(b, d);
    out[idx] = v;
    outh[idx] = (_Float16)v;
}

__global__ __launch_bounds__(256) void embed_tgt_kernel(
    const float* __restrict__ tgt, const float* __restrict__ fw,
    const float* __restrict__ fb, float* __restrict__ out, _Float16* __restrict__ outh)
{
    int idx = blockIdx.x * 256 + threadIdx.x;
    if (idx >= B_ * T_ * DM) return;
    int d = idx & 127;
    int row = idx >> 7;
    int b = row >> 11;
    float v = (tgt[row] * fw[d] + fb[d]) * SQRT_D + pe_val(b, d);
    out[idx] = v;
    outh[idx] = (_Float16)v;
}

// ---------------------------------------------------------------- f16 MFMA GEMM (NT), BM=128 BN=64 BK=64, 256 thr
// MODE 1: f16 C + relu. MODE 2: attention pack (q scaled, k, v-transposed).
template<int MODE>
__global__ __launch_bounds__(256) void gemm_h(
    const _Float16* __restrict__ A, const _Float16* __restrict__ W,
    const float* __restrict__ bias,
    _Float16* __restrict__ Ch,
    _Float16* __restrict__ qo, _Float16* __restrict__ ko, _Float16* __restrict__ vo,
    int M, int N, int K, int L, int Lkp, int part_off, int Lshift)
{
    __shared__ _Float16 As[128][72];
    __shared__ _Float16 Ws[64][72];
    const int t = threadIdx.x;
    const int wave = t >> 6, lane = t & 63;
    const int col16 = lane & 15, grp = lane >> 4;
    const int row0 = blockIdx.x * 128, col0 = blockIdx.y * 64;
    const int wrow0 = (wave >> 1) * 64, wcol0 = (wave & 1) * 32;

    v4f acc[4][2];
    #pragma unroll
    for (int m = 0; m < 4; m++)
        #pragma unroll
        for (int n = 0; n < 2; n++) acc[m][n] = (v4f){0.f, 0.f, 0.f, 0.f};

    for (int k0 = 0; k0 < K; k0 += 64) {
        #pragma unroll
        for (int i = 0; i < 4; i++) {
            int id = i * 256 + t;
            int r = id >> 3, j = id & 7;
            int gr = min(row0 + r, M - 1);
            int4 v = *(const int4*)(A + (size_t)gr * K + k0 + j * 8);
            *(int4*)&As[r][j * 8] = v;
        }
        #pragma unroll
        for (int i = 0; i < 2; i++) {
            int id = i * 256 + t;
            int r = id >> 3, j = id & 7;
            int4 v = *(const int4*)(W + (size_t)(col0 + r) * K + k0 + j * 8);
            *(int4*)&Ws[r][j * 8] = v;
        }
        __syncthreads();
        #pragma unroll
        for (int kk = 0; kk < 4; kk++) {
            v4h a[4], bf[2];
            #pragma unroll
            for (int m = 0; m < 4; m++)
                a[m] = *(const v4h*)&As[wrow0 + m * 16 + col16][kk * 16 + grp * 4];
            #pragma unroll
            for (int n = 0; n < 2; n++)
                bf[n] = *(const v4h*)&Ws[wcol0 + n * 16 + col16][kk * 16 + grp * 4];
            #pragma unroll
            for (int m = 0; m < 4; m++)
                #pragma unroll
                for (int n = 0; n < 2; n++)
                    acc[m][n] = __builtin_amdgcn_mfma_f32_16x16x16f16(a[m], bf[n], acc[m][n], 0, 0, 0);
        }
        __syncthreads();
    }

    #pragma unroll
    for (int n = 0; n < 2; n++) {
        int gcol = col0 + wcol0 + n * 16 + col16;
        float bv = bias[gcol];
        #pragma unroll
        for (int m = 0; m < 4; m++) {
            int rbase = row0 + wrow0 + m * 16 + grp * 4;
            #pragma unroll
            for (int r = 0; r < 4; r++) {
                int grow = rbase + r;
                if (grow >= M) continue;
                float v = acc[m][n][r] + bv;
                if (MODE == 1) {
                    Ch[(size_t)grow * N + gcol] = (_Float16)fmaxf(v, 0.f);
                } else {
                    int pc = gcol + part_off;
                    int part = pc >> 7;
                    int h = (pc >> 4) & 7;
                    int d = pc & 15;
                    int b = Lshift ? (grow >> Lshift) : (grow / L);
                    int pos = grow - b * L;
                    int bh = b * NH + h;
                    if (part == 0)
                        qo[((size_t)bh * L + pos) * 16 + d] = (_Float16)(v * QSCALE);
                    else if (part == 1)
                        ko[((size_t)bh * L + pos) * 16 + d] = (_Float16)v;
                    else
                        vo[((size_t)bh * 16 + d) * Lkp + pos] = (_Float16)v;
                }
            }
        }
    }
}

// ---------------------------------------------------------------- fused GEMM(N=128) + residual + LayerNorm
// MERGE=1: A is implicit = merge of 2 split-KV partials (po/pm/pl).
template<int MERGE>
__global__ __launch_bounds__(128) void gemm_ln(
    const _Float16* __restrict__ A, const _Float16* __restrict__ W,
    const float* __restrict__ bias, const float* __restrict__ res,
    const float* __restrict__ g, const float* __restrict__ bt,
    const _Float16* __restrict__ po, const float* __restrict__ pm, const float* __restrict__ pl,
    float* __restrict__ yout, _Float16* __restrict__ youth, int M, int K)
{
    __shared__ _Float16 As[32][72];
    __shared__ _Float16 Ws[128][72];
    const int t = threadIdx.x;
    const int wave = t >> 6, lane = t & 63;
    const int col16 = lane & 15, grp = lane >> 4;
    const int row0 = blockIdx.x * 32;

    v4f acc[8];
    #pragma unroll
    for (int n = 0; n < 8; n++) acc[n] = (v4f){0.f, 0.f, 0.f, 0.f};

    for (int k0 = 0; k0 < K; k0 += 64) {
        #pragma unroll
        for (int i = 0; i < 2; i++) {
            int id = i * 128 + t;            // 0..255
            int r = id >> 3, j = id & 7;
            int grow = min(row0 + r, M - 1);
            if (MERGE) {
                int dim0 = k0 + j * 8;
                int h = dim0 >> 4;
                int doff = dim0 & 8;
                int b = grow >> 11, q = grow & 2047;
                size_t i0 = ((size_t)(b * 2 + 0) * NH + h) * T_ + q;
                size_t i1 = ((size_t)(b * 2 + 1) * NH + h) * T_ + q;
                float m0 = pm[i0], m1 = pm[i1];
                float MM = fmaxf(m0, m1);
                float w0 = fexp2(m0 - MM) * pl[i0];
                float w1 = fexp2(m1 - MM) * pl[i1];
                float inv = 1.0f / (w0 + w1);
                w0 *= inv; w1 *= inv;
                v8h o0 = *(const v8h*)&po[i0 * 16 + doff];
                v8h o1 = *(const v8h*)&po[i1 * 16 + doff];
                v8h mrg;
                #pragma unroll
                for (int e = 0; e < 8; e++)
                    mrg[e] = (_Float16)((float)o0[e] * w0 + (float)o1[e] * w1);
                *(v8h*)&As[r][j * 8] = mrg;
            } else {
                int4 v = *(const int4*)(A + (size_t)grow * K + k0 + j * 8);
                *(int4*)&As[r][j * 8] = v;
            }
        }
        #pragma unroll
        for (int i = 0; i < 8; i++) {
            int id = i * 128 + t;            // 0..1023
            int r = id >> 3, j = id & 7;
            int4 v = *(const int4*)(W + (size_t)r * K + k0 + j * 8);
            *(int4*)&Ws[r][j * 8] = v;
        }
        __syncthreads();
        #pragma unroll
        for (int kk = 0; kk < 4; kk++) {
            v4h a = *(const v4h*)&As[wave * 16 + col16][kk * 16 + grp * 4];
            #pragma unroll
            for (int n = 0; n < 8; n++) {
                v4h bf = *(const v4h*)&Ws[n * 16 + col16][kk * 16 + grp * 4];
                acc[n] = __builtin_amdgcn_mfma_f32_16x16x16f16(a, bf, acc[n], 0, 0, 0);
            }
        }
        __syncthreads();
    }

    float bv[8], gv[8], btv[8];
    #pragma unroll
    for (int n = 0; n < 8; n++) {
        bv[n]  = bias[col16 + 16 * n];
        gv[n]  = g[col16 + 16 * n];
        btv[n] = bt[col16 + 16 * n];
    }
    #pragma unroll
    for (int r = 0; r < 4; r++) {
        int row = row0 + wave * 16 + grp * 4 + r;
        if (row < M) {
            float x[8];
            float sum = 0.f;
            #pragma unroll
            for (int n = 0; n < 8; n++) {
                x[n] = acc[n][r] + bv[n] + res[(size_t)row * DM + col16 + 16 * n];
                sum += x[n];
            }
            sum += __shfl_xor(sum, 1, 64);
            sum += __shfl_xor(sum, 2, 64);
            sum += __shfl_xor(sum, 4, 64);
            sum += __shfl_xor(sum, 8, 64);
            float mean = sum * (1.0f / 128.0f);
            float vs = 0.f;
            #pragma unroll
            for (int n = 0; n < 8; n++) {
                x[n] -= mean;
                vs += x[n] * x[n];
            }
            vs += __shfl_xor(vs, 1, 64);
            vs += __shfl_xor(vs, 2, 64);
            vs += __shfl_xor(vs, 4, 64);
            vs += __shfl_xor(vs, 8, 64);
            float rstd = rsqrtf(vs * (1.0f / 128.0f) + 1e-5f);
            #pragma unroll
            for (int n = 0; n < 8; n++) {
                float o = x[n] * rstd * gv[n] + btv[n];
                yout[(size_t)row * DM + col16 + 16 * n] = o;
                youth[(size_t)row * DM + col16 + 16 * n] = (_Float16)o;
            }
        }
    }
}

// ---------------------------------------------------------------- MFMA flash attention v3: LDS-staged K/V (dbuf), defer-max
// qh: [B,H,Lq,16] (scaled by QSCALE), kh: [B,H,Lk,16], vth: [B,H,16,Lkp]
// FINAL=1: normalized rows -> outh [B*Lq,128].  FINAL=0: partials po/pm/pl (zb = b*NS+split).
// grid (ceil(Lq/64), H, B*NS), 256 thr = 4 waves. Waves 0-1 stage K chunk, 2-3 stage V^T chunk.
template<int FINAL>
__global__ __launch_bounds__(256, 6) void attn_p3(
    const _Float16* __restrict__ qh, const _Float16* __restrict__ kh,
    const _Float16* __restrict__ vth, _Float16* __restrict__ outh,
    _Float16* __restrict__ po, float* __restrict__ pm, float* __restrict__ pl,
    int Lq, int Lk, int Lkp, int NS)
{
    __shared__ _Float16 KV[2][2048];   // per buf: [0,1024) = K[64][16], [1024,2048) = V^T swizzled [16][64]
    const int zb = blockIdx.z;
    const int b = zb / NS, split = zb - b * NS;
    const int h = blockIdx.y;
    const int wave = threadIdx.x >> 6, lane = threadIdx.x & 63;
    const int col16 = lane & 15, grp = lane >> 4;
    const int bh = b * NH + h;
    const int qrow = (blockIdx.x * 4 + wave) * 16 + col16;
    const int qcl = min(qrow, Lq - 1);

    v4h q_frag = *(const v4h*)(qh + ((size_t)bh * Lq + qcl) * 16 + grp * 4);
    const char* kbB = (const char*)(kh + (size_t)bh * Lk * 16);
    const char* vbB = (const char*)(vth + (size_t)bh * 16 * Lkp);
    const int LkpB = Lkp * 2;

    const int kvLen = Lk / NS;
    const int kv0 = split * kvLen;
    const int kvEnd = kv0 + kvLen;

    // precompute per-lane staging offsets
    const int vd = (wave & 1) * 8 + (lane >> 3);          // for waves 2,3: d row
    const long vsrc_off = (long)vd * LkpB + (((lane & 7) * 16) ^ ((vd & 7) << 4));
    char* ldsK = (char*)&KV[0][0] + wave * 1024;          // waves 0,1
    char* ldsV = (char*)&KV[0][0] + 2048 + (wave & 1) * 1024;  // waves 2,3

    auto stage = [&](int buf, int kc) {
        if (wave < 2)
            gload_lds16(kbB + (long)kc * 32 + wave * 1024 + lane * 16,
                        ldsK + buf * 4096);
        else
            gload_lds16(vbB + (long)kc * 2 + vsrc_off,
                        ldsV + buf * 4096);
    };

    float m = -1e30f;
    v4f l4 = {0.f, 0.f, 0.f, 0.f};
    v4f oa = {0.f, 0.f, 0.f, 0.f}, ob = {0.f, 0.f, 0.f, 0.f};

    stage(0, kv0);
    __syncthreads();

    int nChunks = (kvLen + 63) >> 6;
    int cur = 0;
    for (int ci = 0; ci < nChunks; ci++, cur ^= 1) {
        int kc = kv0 + ci * 64;
        if (ci + 1 < nChunks) stage(cur ^ 1, kc + 64);

        const char* base = (const char*)&KV[cur][0];
        v4f s4[4];
        #pragma unroll
        for (int sub = 0; sub < 4; sub++) {
            v4h k_frag = *(const v4h*)(base + (sub * 16 + col16) * 32 + grp * 8);
            s4[sub] = __builtin_amdgcn_mfma_f32_16x16x16f16(
                          k_frag, q_frag, (v4f){0.f, 0.f, 0.f, 0.f}, 0, 0, 0);
        }
        if (kc + 64 > kvEnd) {
            #pragma unroll
            for (int sub = 0; sub < 4; sub++)
                #pragma unroll
                for (int r = 0; r < 4; r++) {
                    int key = kc + sub * 16 + grp * 4 + r;
                    if (key >= kvEnd) s4[sub][r] = -1e30f;
                }
        }
        // chunk max (tree)
        float c0 = fmaxf(fmaxf(s4[0][0], s4[0][1]), fmaxf(s4[0][2], s4[0][3]));
        float c1 = fmaxf(fmaxf(s4[1][0], s4[1][1]), fmaxf(s4[1][2], s4[1][3]));
        float c2 = fmaxf(fmaxf(s4[2][0], s4[2][1]), fmaxf(s4[2][2], s4[2][3]));
        float c3 = fmaxf(fmaxf(s4[3][0], s4[3][1]), fmaxf(s4[3][2], s4[3][3]));
        float cm = fmaxf(fmaxf(c0, c1), fmaxf(c2, c3));
        if (__any(cm > m + 8.0f)) {
            float nm = fmaxf(cm, m);
            nm = fmaxf(nm, __shfl_xor(nm, 16, 64));
            nm = fmaxf(nm, __shfl_xor(nm, 32, 64));
            float corr = fexp2(m - nm);
            l4[0] *= corr; l4[1] *= corr; l4[2] *= corr; l4[3] *= corr;
            oa[0] *= corr; oa[1] *= corr; oa[2] *= corr; oa[3] *= corr;
            ob[0] *= corr; ob[1] *= corr; ob[2] *= corr; ob[3] *= corr;
            m = nm;
        }
        v4h ph[4];
        #pragma unroll
        for (int sub = 0; sub < 4; sub++) {
            float p0 = fexp2(s4[sub][0] - m);
            float p1 = fexp2(s4[sub][1] - m);
            float p2 = fexp2(s4[sub][2] - m);
            float p3 = fexp2(s4[sub][3] - m);
            l4[0] += p0; l4[1] += p1; l4[2] += p2; l4[3] += p3;
            ph[sub] = (v4h){ (_Float16)p0, (_Float16)p1, (_Float16)p2, (_Float16)p3 };
        }
        #pragma unroll
        for (int sub = 0; sub < 4; sub++) {
            int vbyte = 2048 + (col16 << 7) + ((sub * 32 + grp * 8) ^ ((col16 & 7) << 4));
            v4h vt_frag = *(const v4h*)(base + vbyte);
            if (sub & 2)
                ob = __builtin_amdgcn_mfma_f32_16x16x16f16(vt_frag, ph[sub], ob, 0, 0, 0);
            else
                oa = __builtin_amdgcn_mfma_f32_16x16x16f16(vt_frag, ph[sub], oa, 0, 0, 0);
        }
        __syncthreads();
    }

    float l = (l4[0] + l4[1]) + (l4[2] + l4[3]);
    l += __shfl_xor(l, 16, 64);
    l += __shfl_xor(l, 32, 64);
    float inv = 1.0f / l;
    v4f o_acc = {oa[0] + ob[0], oa[1] + ob[1], oa[2] + ob[2], oa[3] + ob[3]};
    if (qrow < Lq) {
        v4h ov = { (_Float16)(o_acc[0] * inv), (_Float16)(o_acc[1] * inv),
                   (_Float16)(o_acc[2] * inv), (_Float16)(o_acc[3] * inv) };
        if (FINAL) {
            *(v4h*)(outh + ((size_t)b * Lq + qrow) * DM + h * DH + grp * 4) = ov;
        } else {
            size_t pidx = ((size_t)zb * NH + h) * Lq + qrow;
            *(v4h*)(po + pidx * 16 + grp * 4) = ov;
            if (grp == 0) { pm[pidx] = m; pl[pidx] = l; }
        }
    }
}

// ---------------------------------------------------------------- residual + LayerNorm (standalone, encoder final)
__global__ __launch_bounds__(256) void add_ln_kernel(
    float* __restrict__ y, const float* __restrict__ res,
    const float* __restrict__ g, const float* __restrict__ bta,
    _Float16* __restrict__ yh, int M)
{
    int row = blockIdx.x * 4 + (threadIdx.x >> 6);
    int lane = threadIdx.x & 63;
    if (row >= M) return;
    float* yr = y + (size_t)row * DM;
    float x0 = yr[lane], x1 = yr[lane + 64];
    if (res) {
        const float* rr = res + (size_t)row * DM;
        x0 += rr[lane]; x1 += rr[lane + 64];
    }
    float sum = x0 + x1;
    #pragma unroll
    for (int off = 32; off > 0; off >>= 1) sum += __shfl_xor(sum, off, 64);
    float mean = sum * (1.0f / 128.0f);
    float d0 = x0 - mean, d1 = x1 - mean;
    float vs = d0 * d0 + d1 * d1;
    #pragma unroll
    for (int off = 32; off > 0; off >>= 1) vs += __shfl_xor(vs, off, 64);
    float rstd = rsqrtf(vs * (1.0f / 128.0f) + 1e-5f);
    float o0 = d0 * rstd * g[lane]      + bta[lane];
    float o1 = d1 * rstd * g[lane + 64] + bta[lane + 64];
    yr[lane] = o0; yr[lane + 64] = o1;
    _Float16* yhr = yh + (size_t)row * DM;
    yhr[lane] = (_Float16)o0; yhr[lane + 64] = (_Float16)o1;
}

// ---------------------------------------------------------------- final: LN(y)*g+b, dot fc, out = tgt + eta*(.)
__global__ __launch_bounds__(256) void final_ln_kernel(
    const float* __restrict__ y, const float* __restrict__ tgt,
    const float* __restrict__ g, const float* __restrict__ bta,
    const float* __restrict__ fcw, const float* __restrict__ fcb,
    float* __restrict__ out)
{
    int row = blockIdx.x * 4 + (threadIdx.x >> 6);
    int lane = threadIdx.x & 63;
    const float* yr = y + (size_t)row * DM;
    float x0 = yr[lane], x1 = yr[lane + 64];
    float sum = x0 + x1;
    #pragma unroll
    for (int off = 32; off > 0; off >>= 1) sum += __shfl_xor(sum, off, 64);
    float mean = sum * (1.0f / 128.0f);
    float d0 = x0 - mean, d1 = x1 - mean;
    float vs = d0 * d0 + d1 * d1;
    #pragma unroll
    for (int off = 32; off > 0; off >>= 1) vs += __shfl_xor(vs, off, 64);
    float rstd = rsqrtf(vs * (1.0f / 128.0f) + 1e-5f);
    float o0 = d0 * rstd * g[lane]      + bta[lane];
    float o1 = d1 * rstd * g[lane + 64] + bta[lane + 64];
    float a = o0 * fcw[lane] + o1 * fcw[lane + 64];
    #pragma unroll
    for (int off = 32; off > 0; off >>= 1) a += __shfl_xor(a, off, 64);
    if (lane == 0) out[row] = tgt[row] + 1.0e-3f * (a + fcb[0]);
}

// ---------------------------------------------------------------- launcher
extern "C" void kernel_launch(void* const* d_in, const int* in_sizes, int n_in,
                              void* d_out, int out_size, void* d_ws, size_t ws_size,
                              hipStream_t stream)
{
    (void)in_sizes; (void)n_in; (void)out_size; (void)ws_size;
    const int*   src     = (const int*)  d_in[0];
    const float* tgt     = (const float*)d_in[1];
    const float* emb     = (const float*)d_in[2];
    const float* femb_w  = (const float*)d_in[3];
    const float* femb_b  = (const float*)d_in[4];
    const float* enc_inw = (const float*)d_in[5];
    const float* enc_inb = (const float*)d_in[6];
    const float* enc_ow  = (const float*)d_in[7];
    const float* enc_ob  = (const float*)d_in[8];
    const float* enc_l1g = (const float*)d_in[9];
    const float* enc_l1b = (const float*)d_in[10];
    const float* enc_l2g = (const float*)d_in[11];
    const float* enc_l2b = (const float*)d_in[12];
    const float* enc_f1w = (const float*)d_in[13];
    const float* enc_f1b = (const float*)d_in[14];
    const float* enc_f2w = (const float*)d_in[15];
    const float* enc_f2b = (const float*)d_in[16];
    const float* enc_ng  = (const float*)d_in[17];
    const float* enc_nb  = (const float*)d_in[18];
    const float* dec_inw = (const float*)d_in[19];
    const float* dec_inb = (const float*)d_in[20];
    const float* dec_ow  = (const float*)d_in[21];
    const float* dec_ob  = (const float*)d_in[22];
    const float* dec_cinw= (const float*)d_in[23];
    const float* dec_cinb= (const float*)d_in[24];
    const float* dec_cow = (const float*)d_in[25];
    const float* dec_cob = (const float*)d_in[26];
    const float* dec_l1g = (const float*)d_in[27];
    const float* dec_l1b = (const float*)d_in[28];
    const float* dec_l2g = (const float*)d_in[29];
    const float* dec_l2b = (const float*)d_in[30];
    const float* dec_l3g = (const float*)d_in[31];
    const float* dec_l3b = (const float*)d_in[32];
    const float* dec_f1w = (const float*)d_in[33];
    const float* dec_f1b = (const float*)d_in[34];
    const float* dec_f2w = (const float*)d_in[35];
    const float* dec_f2b = (const float*)d_in[36];
    const float* dec_ng  = (const float*)d_in[37];
    const float* dec_nb  = (const float*)d_in[38];
    const float* fc_w    = (const float*)d_in[39];
    const float* fc_b    = (const float*)d_in[40];

    // ---- workspace layout ----
    float* ws = (float*)d_ws;
    float* mem  = ws;                        // 51200
    float* ybuf = ws + 51200;                // 1048576
    float* pm   = ws + 51200 + 1048576;      // 131072  (2*4*8*2048)
    float* pl   = pm + 131072;               // 131072
    _Float16* hb = (_Float16*)(pl + 131072);
    _Float16* mem_h  = hb;                   // 51200
    _Float16* ybuf_h = hb + 51200;           // 1048576
    _Float16* aout_h = hb + 1099776;         // 1048576
    _Float16* wh     = hb + 2148352;         // 2752512
    _Float16* po     = hb + 4900864;         // 2097152 (normalized f16 partials)
    _Float16* arena  = hb + 6998016;         // 4194304
    _Float16* QH  = arena;
    _Float16* KH  = arena + 1048576;
    _Float16* VTH = arena + 2097152;
    _Float16* BIGH = arena;                  // FFN hidden reuses attn packs

    const long W_ENC_INW = 0,       W_ENC_OW = 294912,  W_ENC_F1W = 393216,  W_ENC_F2W = 786432;
    const long W_DEC_INW = 1179648, W_DEC_OW = 1474560, W_DEC_CINW = 1572864, W_DEC_COW = 1867776;
    const long W_DEC_F1W = 1966080, W_DEC_F2W = 2359296;

    conv_w<<<dim3(384, 10), 256, 0, stream>>>(enc_inw, enc_ow, enc_f1w, enc_f2w,
                                              dec_inw, dec_ow, dec_cinw, dec_cow,
                                              dec_f1w, dec_f2w, wh);

    // ---------------- encoder (M = 400 rows) ----------------
    embed_src_kernel<<<200, 256, 0, stream>>>(src, emb, mem, mem_h);
    for (int i = 0; i < NL; i++) {
        gemm_h<2><<<dim3(4, 6), 256, 0, stream>>>(mem_h, wh + W_ENC_INW + i * 49152, enc_inb + i * 384,
            nullptr, QH, KH, VTH, 400, 384, 128, 100, 128, 0, 0);
        attn_p3<1><<<dim3(2, NH, B_), 256, 0, stream>>>(QH, KH, VTH, aout_h,
            nullptr, nullptr, nullptr, 100, 100, 128, 1);
        gemm_ln<0><<<13, 128, 0, stream>>>(aout_h, wh + W_ENC_OW + i * 16384, enc_ob + i * 128,
            mem, enc_l1g + i * 128, enc_l1b + i * 128, nullptr, nullptr, nullptr, mem, mem_h, 400, 128);
        gemm_h<1><<<dim3(4, 8), 256, 0, stream>>>(mem_h, wh + W_ENC_F1W + i * 65536, enc_f1b + i * 512,
            BIGH, nullptr, nullptr, nullptr, 400, 512, 128, 0, 0, 0, 0);
        gemm_ln<0><<<13, 128, 0, stream>>>(BIGH, wh + W_ENC_F2W + i * 65536, enc_f2b + i * 128,
            mem, enc_l2g + i * 128, enc_l2b + i * 128, nullptr, nullptr, nullptr, mem, mem_h, 400, 512);
    }
    add_ln_kernel<<<100, 256, 0, stream>>>(mem, nullptr, enc_ng, enc_nb, mem_h, 400);

    // ---------------- decoder (M = 8192 rows) ----------------
    embed_tgt_kernel<<<4096, 256, 0, stream>>>(tgt, femb_w, femb_b, ybuf, ybuf_h);
    for (int i = 0; i < NL; i++) {
        // self-attention (split-KV x2) + fused merge in gemm_ln
        gemm_h<2><<<dim3(64, 6), 256, 0, stream>>>(ybuf_h, wh + W_DEC_INW + i * 49152, dec_inb + i * 384,
            nullptr, QH, KH, VTH, 8192, 384, 128, 2048, 2048, 0, 11);
        attn_p3<0><<<dim3(32, NH, B_ * 2), 256, 0, stream>>>(QH, KH, VTH, nullptr,
            po, pm, pl, 2048, 2048, 2048, 2);
        gemm_ln<1><<<256, 128, 0, stream>>>(nullptr, wh + W_DEC_OW + i * 16384, dec_ob + i * 128,
            ybuf, dec_l1g + i * 128, dec_l1b + i * 128, po, pm, pl, ybuf, ybuf_h, 8192, 128);
        // cross-attention
        gemm_h<2><<<dim3(64, 2), 256, 0, stream>>>(ybuf_h, wh + W_DEC_CINW + i * 49152, dec_cinb + i * 384,
            nullptr, QH, nullptr, nullptr, 8192, 128, 128, 2048, 2048, 0, 11);
        gemm_h<2><<<dim3(4, 4), 256, 0, stream>>>(mem_h, wh + W_DEC_CINW + i * 49152 + 16384, dec_cinb + i * 384 + 128,
            nullptr, nullptr, KH, VTH, 400, 256, 128, 100, 128, 128, 0);
        attn_p3<1><<<dim3(32, NH, B_), 256, 0, stream>>>(QH, KH, VTH, aout_h,
            nullptr, nullptr, nullptr, 2048, 100, 128, 1);
        gemm_ln<0><<<256, 128, 0, stream>>>(aout_h, wh + W_DEC_COW + i * 16384, dec_cob + i * 128,
            ybuf, dec_l2g + i * 128, dec_l2b + i * 128, nullptr, nullptr, nullptr, ybuf, ybuf_h, 8192, 128);
        // FFN
        gemm_h<1><<<dim3(64, 8), 256, 0, stream>>>(ybuf_h, wh + W_DEC_F1W + i * 65536, dec_f1b + i * 512,
            BIGH, nullptr, nullptr, nullptr, 8192, 512, 128, 0, 0, 0, 0);
        gemm_ln<0><<<256, 128, 0, stream>>>(BIGH, wh + W_DEC_F2W + i * 65536, dec_f2b + i * 128,
            ybuf, dec_l3g + i * 128, dec_l3b + i * 128, nullptr, nullptr, nullptr, ybuf, ybuf_h, 8192, 512);
    }
    final_ln_kernel<<<2048, 256, 0, stream>>>(ybuf, tgt, dec_ng, dec_nb, fc_w, fc_b, (float*)d_out);
}